// Round 1
// baseline (1743.270 us; speedup 1.0000x reference)
//
#include <hip/hip_runtime.h>

#define D     128
#define NCLI  100000
#define NAGG  1000
#define NLAYER 3

static __device__ __forceinline__ float leaky(float x) { return x >= 0.f ? x : 0.1f * x; }

// ---------------- CSR build ----------------

// histogram with LDS privatization for small bin count (NAGG=1000)
__global__ void hist_small(const int* __restrict__ dst, int E, int* __restrict__ cnt) {
    __shared__ int h[NAGG];
    for (int i = threadIdx.x; i < NAGG; i += blockDim.x) h[i] = 0;
    __syncthreads();
    int stride = gridDim.x * blockDim.x;
    for (int e = blockIdx.x * blockDim.x + threadIdx.x; e < E; e += stride)
        atomicAdd(&h[dst[e]], 1);
    __syncthreads();
    for (int i = threadIdx.x; i < NAGG; i += blockDim.x)
        if (h[i]) atomicAdd(&cnt[i], h[i]);
}

__global__ void hist_large(const int* __restrict__ dst, int E, int* __restrict__ cnt) {
    int stride = gridDim.x * blockDim.x;
    for (int e = blockIdx.x * blockDim.x + threadIdx.x; e < E; e += stride)
        atomicAdd(&cnt[dst[e]], 1);
}

// inclusive scan of n<=1024 in one block; writes rowptr[0..n]
__global__ void scan_1024(const int* __restrict__ cnt, int n, int* __restrict__ rowptr) {
    __shared__ int sh[1024];
    int t = threadIdx.x;
    int v = (t < n) ? cnt[t] : 0;
    sh[t] = v;
    __syncthreads();
    for (int off = 1; off < 1024; off <<= 1) {
        int x = (t >= off) ? sh[t - off] : 0;
        __syncthreads();
        sh[t] += x;
        __syncthreads();
    }
    if (t == 0) rowptr[0] = 0;
    if (t < n) rowptr[t + 1] = sh[t];
}

__global__ void scan_chunk(const int* __restrict__ cnt, int n, int* __restrict__ rowptr,
                           int* __restrict__ bsums) {
    __shared__ int sh[1024];
    int t = threadIdx.x;
    int i = blockIdx.x * 1024 + t;
    int v = (i < n) ? cnt[i] : 0;
    sh[t] = v;
    __syncthreads();
    for (int off = 1; off < 1024; off <<= 1) {
        int x = (t >= off) ? sh[t - off] : 0;
        __syncthreads();
        sh[t] += x;
        __syncthreads();
    }
    if (i < n) rowptr[i + 1] = sh[t];
    if (t == 1023) bsums[blockIdx.x] = sh[t];
}

__global__ void scan_bsums(const int* __restrict__ bsums, int nb, int* __restrict__ boffs) {
    __shared__ int sh[128];
    int t = threadIdx.x;
    int v = (t < nb) ? bsums[t] : 0;
    sh[t] = v;
    __syncthreads();
    for (int off = 1; off < 128; off <<= 1) {
        int x = (t >= off) ? sh[t - off] : 0;
        __syncthreads();
        sh[t] += x;
        __syncthreads();
    }
    if (t < nb) boffs[t] = sh[t] - v;  // exclusive
}

__global__ void scan_apply(int n, int* __restrict__ rowptr, const int* __restrict__ boffs) {
    int i = blockIdx.x * 1024 + threadIdx.x;
    if (i < n) rowptr[i + 1] += boffs[blockIdx.x];
    if (i == 0) rowptr[0] = 0;
}

__global__ void init_cursors(const int* __restrict__ rpa, int* __restrict__ cura,
                             const int* __restrict__ rpc, int* __restrict__ curc) {
    int i = blockIdx.x * 256 + threadIdx.x;
    if (i < NAGG) cura[i] = rpa[i];
    if (i < NCLI) curc[i] = rpc[i];
}

__global__ void scatter_edges(const int* __restrict__ src, const int* __restrict__ dst, int E,
                              int* __restrict__ cursor, int* __restrict__ col) {
    int stride = gridDim.x * blockDim.x;
    for (int e = blockIdx.x * blockDim.x + threadIdx.x; e < E; e += stride) {
        int pos = atomicAdd(&cursor[dst[e]], 1);
        col[pos] = src[e];
    }
}

// ---------------- layer kernels ----------------

// Y = X @ W for NAGG rows (one block per row, 128 threads)
__global__ void mm_small(const float* __restrict__ X, const float* __restrict__ W,
                         float* __restrict__ Y) {
    __shared__ float xr[D];
    int i = blockIdx.x, j = threadIdx.x;
    xr[j] = X[i * D + j];
    __syncthreads();
    float acc = 0.f;
#pragma unroll 8
    for (int k = 0; k < D; k++) acc += xr[k] * W[k * D + j];
    Y[i * D + j] = acc;
}

// mean over CSR segment of X rows -> out (one block per agg node, 128 threads)
__global__ void mean_agg(const float* __restrict__ X, const int* __restrict__ rowptr,
                         const int* __restrict__ col, float* __restrict__ out) {
    __shared__ int cols[128];
    int i = blockIdx.x, j = threadIdx.x;
    int beg = rowptr[i], end = rowptr[i + 1];
    float s0 = 0.f, s1 = 0.f, s2 = 0.f, s3 = 0.f;
    for (int base = beg; base < end; base += 128) {
        int m = min(128, end - base);
        if (j < m) cols[j] = col[base + j];
        __syncthreads();
        int t = 0;
        for (; t + 4 <= m; t += 4) {
            int r0 = cols[t], r1 = cols[t + 1], r2 = cols[t + 2], r3 = cols[t + 3];
            s0 += X[r0 * D + j];
            s1 += X[r1 * D + j];
            s2 += X[r2 * D + j];
            s3 += X[r3 * D + j];
        }
        for (; t < m; t++) s0 += X[cols[t] * D + j];
        __syncthreads();
    }
    float c = (float)(end - beg);
    out[i * D + j] = (s0 + s1 + s2 + s3) / fmaxf(c, 1.f);
}

// xa_out = leaky(mean_a @ Wl + xa_old @ Wr + b)   (one block per agg row)
__global__ void new_a_kernel(const float* __restrict__ mean_a, const float* __restrict__ xa_old,
                             const float* __restrict__ Wl, const float* __restrict__ Wr,
                             const float* __restrict__ b, float* __restrict__ xa_out) {
    __shared__ float mr[D], xr[D];
    int i = blockIdx.x, j = threadIdx.x;
    mr[j] = mean_a[i * D + j];
    xr[j] = xa_old[i * D + j];
    __syncthreads();
    float acc = b[j];
#pragma unroll 4
    for (int k = 0; k < D; k++) acc += mr[k] * Wl[k * D + j] + xr[k] * Wr[k * D + j];
    xa_out[i * D + j] = leaky(acc);
}

// Y = X @ W + b, register-tiled: block = 256 threads, 32 rows x 128 cols, 4x4 per thread
__global__ __launch_bounds__(256) void gemm_bias(const float* __restrict__ X,
                                                 const float* __restrict__ W,
                                                 const float* __restrict__ b,
                                                 float* __restrict__ Y, int M) {
    __shared__ float xs[32][D];
    int tid = threadIdx.x;
    int m0 = blockIdx.x * 32;
    for (int idx = tid; idx < 32 * D; idx += 256) {
        int r = idx >> 7, c = idx & 127;
        int row = m0 + r;
        xs[r][c] = (row < M) ? X[row * D + c] : 0.f;
    }
    __syncthreads();
    int jg = tid & 31;   // cols jg*4 .. jg*4+3
    int cg = tid >> 5;   // rows cg*4 .. cg*4+3
    float a00 = 0, a01 = 0, a02 = 0, a03 = 0;
    float a10 = 0, a11 = 0, a12 = 0, a13 = 0;
    float a20 = 0, a21 = 0, a22 = 0, a23 = 0;
    float a30 = 0, a31 = 0, a32 = 0, a33 = 0;
#pragma unroll 4
    for (int k = 0; k < D; k++) {
        float4 w = *(const float4*)&W[k * D + jg * 4];
        float x0 = xs[cg * 4 + 0][k];
        float x1 = xs[cg * 4 + 1][k];
        float x2 = xs[cg * 4 + 2][k];
        float x3 = xs[cg * 4 + 3][k];
        a00 += x0 * w.x; a01 += x0 * w.y; a02 += x0 * w.z; a03 += x0 * w.w;
        a10 += x1 * w.x; a11 += x1 * w.y; a12 += x1 * w.z; a13 += x1 * w.w;
        a20 += x2 * w.x; a21 += x2 * w.y; a22 += x2 * w.z; a23 += x2 * w.w;
        a30 += x3 * w.x; a31 += x3 * w.y; a32 += x3 * w.z; a33 += x3 * w.w;
    }
    float4 bv = *(const float4*)&b[jg * 4];
    float4 o;
    int row = m0 + cg * 4;
    if (row + 0 < M) { o = make_float4(a00 + bv.x, a01 + bv.y, a02 + bv.z, a03 + bv.w); *(float4*)&Y[(row + 0) * D + jg * 4] = o; }
    if (row + 1 < M) { o = make_float4(a10 + bv.x, a11 + bv.y, a12 + bv.z, a13 + bv.w); *(float4*)&Y[(row + 1) * D + jg * 4] = o; }
    if (row + 2 < M) { o = make_float4(a20 + bv.x, a21 + bv.y, a22 + bv.z, a23 + bv.w); *(float4*)&Y[(row + 2) * D + jg * 4] = o; }
    if (row + 3 < M) { o = make_float4(a30 + bv.x, a31 + bv.y, a32 + bv.z, a33 + bv.w); *(float4*)&Y[(row + 3) * D + jg * 4] = o; }
}

// Y[i] = leaky(Y[i] + mean_e ya[col[e]])   (one wave per client, 4 clients/block)
__global__ void agg_c_leaky(const float* __restrict__ ya, const int* __restrict__ rowptr,
                            const int* __restrict__ col, float* __restrict__ Y) {
    int lane = threadIdx.x & 63;
    int gid = blockIdx.x * 4 + (threadIdx.x >> 6);
    if (gid >= NCLI) return;
    int beg = rowptr[gid], end = rowptr[gid + 1];
    float s0 = 0.f, s1 = 0.f;
    for (int e = beg; e < end; e++) {
        int r = col[e];
        s0 += ya[r * D + lane];
        s1 += ya[r * D + 64 + lane];
    }
    float c = fmaxf((float)(end - beg), 1.f);
    int idx = gid * D + lane;
    Y[idx] = leaky(Y[idx] + s0 / c);
    Y[idx + 64] = leaky(Y[idx + 64] + s1 / c);
}

// out[i] = xc[i] . W_lin + b_lin  (one wave per client)
__global__ void out_kernel(const float* __restrict__ xc, const float* __restrict__ Wlin,
                           const float* __restrict__ blin, float* __restrict__ out) {
    int lane = threadIdx.x & 63;
    int gid = blockIdx.x * 4 + (threadIdx.x >> 6);
    if (gid >= NCLI) return;
    float v = xc[gid * D + lane] * Wlin[lane] + xc[gid * D + 64 + lane] * Wlin[64 + lane];
#pragma unroll
    for (int off = 32; off > 0; off >>= 1) v += __shfl_down(v, off);
    if (lane == 0) out[gid] = v + blin[0];
}

extern "C" void kernel_launch(void* const* d_in, const int* in_sizes, int n_in,
                              void* d_out, int out_size, void* d_ws, size_t ws_size,
                              hipStream_t stream) {
    const float* x_clients = (const float*)d_in[0];
    const float* x_agg     = (const float*)d_in[1];
    const int*   c2a_src   = (const int*)d_in[2];
    const int*   c2a_dst   = (const int*)d_in[3];
    const int*   a2c_src   = (const int*)d_in[4];
    const int*   a2c_dst   = (const int*)d_in[5];
    const float* Wl_c2a    = (const float*)d_in[6];
    const float* Wr_c2a    = (const float*)d_in[7];
    const float* b_c2a     = (const float*)d_in[8];
    const float* Wl_a2c    = (const float*)d_in[9];
    const float* Wr_a2c    = (const float*)d_in[10];
    const float* b_a2c     = (const float*)d_in[11];
    const float* W_lin     = (const float*)d_in[12];
    const float* b_lin     = (const float*)d_in[13];
    float* out = (float*)d_out;
    const int E = in_sizes[2];

    char* p = (char*)d_ws;
    auto alloc = [&](size_t bytes) {
        char* r = p;
        p += (bytes + 255) & ~(size_t)255;
        return r;
    };
    float* xcA = (float*)alloc(sizeof(float) * NCLI * D);
    float* xcB = (float*)alloc(sizeof(float) * NCLI * D);
    float* xa  = (float*)alloc(sizeof(float) * NAGG * D);
    float* ya  = (float*)alloc(sizeof(float) * NAGG * D);
    float* ma  = (float*)alloc(sizeof(float) * NAGG * D);
    int* cnt_a = (int*)alloc(sizeof(int) * NAGG);
    int* rp_a  = (int*)alloc(sizeof(int) * (NAGG + 1));
    int* cur_a = (int*)alloc(sizeof(int) * NAGG);
    int* cnt_c = (int*)alloc(sizeof(int) * NCLI);
    int* rp_c  = (int*)alloc(sizeof(int) * (NCLI + 1));
    int* cur_c = (int*)alloc(sizeof(int) * NCLI);
    int* bsums = (int*)alloc(sizeof(int) * 128);
    int* boffs = (int*)alloc(sizeof(int) * 128);
    int* col_c2a = (int*)alloc(sizeof(int) * E);
    int* col_a2c = (int*)alloc(sizeof(int) * E);

    hipMemsetAsync(cnt_a, 0, sizeof(int) * NAGG, stream);
    hipMemsetAsync(cnt_c, 0, sizeof(int) * NCLI, stream);

    hist_small<<<256, 256, 0, stream>>>(c2a_dst, E, cnt_a);
    hist_large<<<2048, 256, 0, stream>>>(a2c_dst, E, cnt_c);
    scan_1024<<<1, 1024, 0, stream>>>(cnt_a, NAGG, rp_a);
    int nb = (NCLI + 1023) / 1024;  // 98
    scan_chunk<<<nb, 1024, 0, stream>>>(cnt_c, NCLI, rp_c, bsums);
    scan_bsums<<<1, 128, 0, stream>>>(bsums, nb, boffs);
    scan_apply<<<nb, 1024, 0, stream>>>(NCLI, rp_c, boffs);
    init_cursors<<<(NCLI + 255) / 256, 256, 0, stream>>>(rp_a, cur_a, rp_c, cur_c);
    scatter_edges<<<2048, 256, 0, stream>>>(c2a_src, c2a_dst, E, cur_a, col_c2a);
    scatter_edges<<<2048, 256, 0, stream>>>(a2c_src, a2c_dst, E, cur_c, col_a2c);

    const float* xc_old = x_clients;
    const float* xa_old = x_agg;
    float* xc_bufs[2] = {xcA, xcB};
    for (int l = 0; l < NLAYER; l++) {
        float* xc_new = xc_bufs[l & 1];
        // ya = xa_old @ Wl_a2c[l]   (folds mean_c @ Wl into aggregation of ya rows)
        mm_small<<<NAGG, D, 0, stream>>>(xa_old, Wl_a2c + l * D * D, ya);
        // mean_a over c2a edges of xc_old
        mean_agg<<<NAGG, D, 0, stream>>>(xc_old, rp_a, col_c2a, ma);
        // xa = leaky(mean_a @ Wl_c2a + xa_old @ Wr_c2a + b_c2a)
        new_a_kernel<<<NAGG, D, 0, stream>>>(ma, xa_old, Wl_c2a + l * D * D, Wr_c2a + l * D * D,
                                             b_c2a + l * D, xa);
        // xc_new = xc_old @ Wr_a2c + b_a2c
        gemm_bias<<<(NCLI + 31) / 32, 256, 0, stream>>>(xc_old, Wr_a2c + l * D * D, b_a2c + l * D,
                                                        xc_new, NCLI);
        // xc_new = leaky(xc_new + mean_e ya[src])
        agg_c_leaky<<<(NCLI + 3) / 4, 256, 0, stream>>>(ya, rp_c, col_a2c, xc_new);
        xc_old = xc_new;
        xa_old = xa;
    }
    out_kernel<<<(NCLI + 3) / 4, 256, 0, stream>>>(xc_old, W_lin, b_lin, out);
}

// Round 2
// 1088.050 us; speedup vs baseline: 1.6022x; 1.6022x over previous
//
#include <hip/hip_runtime.h>

#define D      128
#define NCLI   100000
#define NAGG   1000
#define NLAYER 3
#define NBKT   782   // ceil(NCLI/128)

static __device__ __forceinline__ float leaky(float x) { return x >= 0.f ? x : 0.1f * x; }

// ---------------- CSR build ----------------

// global histogram over NAGG bins with LDS privatization
__global__ __launch_bounds__(256) void hist_small(const int* __restrict__ dst, int E,
                                                  int* __restrict__ cnt) {
    __shared__ int h[NAGG];
    for (int i = threadIdx.x; i < NAGG; i += 256) h[i] = 0;
    __syncthreads();
    int stride = gridDim.x * 256;
    for (int e = blockIdx.x * 256 + threadIdx.x; e < E; e += stride)
        atomicAdd(&h[dst[e]], 1);
    __syncthreads();
    for (int i = threadIdx.x; i < NAGG; i += 256)
        if (h[i]) atomicAdd(&cnt[i], h[i]);
}

// global histogram over NBKT buckets (dst>>7)
__global__ __launch_bounds__(256) void bucket_hist(const int* __restrict__ dst, int E,
                                                   int* __restrict__ cnt) {
    __shared__ int h[NBKT];
    for (int i = threadIdx.x; i < NBKT; i += 256) h[i] = 0;
    __syncthreads();
    int stride = gridDim.x * 256;
    for (int e = blockIdx.x * 256 + threadIdx.x; e < E; e += stride)
        atomicAdd(&h[dst[e] >> 7], 1);
    __syncthreads();
    for (int i = threadIdx.x; i < NBKT; i += 256)
        if (h[i]) atomicAdd(&cnt[i], h[i]);
}

// inclusive scan of n<=1024 in one block; writes rowptr[0..n]
__global__ void scan_1024(const int* __restrict__ cnt, int n, int* __restrict__ rowptr) {
    __shared__ int sh[1024];
    int t = threadIdx.x;
    int v = (t < n) ? cnt[t] : 0;
    sh[t] = v;
    __syncthreads();
    for (int off = 1; off < 1024; off <<= 1) {
        int x = (t >= off) ? sh[t - off] : 0;
        __syncthreads();
        sh[t] += x;
        __syncthreads();
    }
    if (t == 0) rowptr[0] = 0;
    if (t < n) rowptr[t + 1] = sh[t];
}

__global__ void scan_chunk(const int* __restrict__ cnt, int n, int* __restrict__ rowptr,
                           int* __restrict__ bsums) {
    __shared__ int sh[1024];
    int t = threadIdx.x;
    int i = blockIdx.x * 1024 + t;
    int v = (i < n) ? cnt[i] : 0;
    sh[t] = v;
    __syncthreads();
    for (int off = 1; off < 1024; off <<= 1) {
        int x = (t >= off) ? sh[t - off] : 0;
        __syncthreads();
        sh[t] += x;
        __syncthreads();
    }
    if (i < n) rowptr[i + 1] = sh[t];
    if (t == 1023) bsums[blockIdx.x] = sh[t];
}

__global__ void scan_bsums(const int* __restrict__ bsums, int nb, int* __restrict__ boffs) {
    __shared__ int sh[128];
    int t = threadIdx.x;
    int v = (t < nb) ? bsums[t] : 0;
    sh[t] = v;
    __syncthreads();
    for (int off = 1; off < 128; off <<= 1) {
        int x = (t >= off) ? sh[t - off] : 0;
        __syncthreads();
        sh[t] += x;
        __syncthreads();
    }
    if (t < nb) boffs[t] = sh[t] - v;  // exclusive
}

__global__ void scan_apply(int n, int* __restrict__ rowptr, const int* __restrict__ boffs) {
    int i = blockIdx.x * 1024 + threadIdx.x;
    if (i < n) rowptr[i + 1] += boffs[blockIdx.x];
    if (i == 0) rowptr[0] = 0;
}

__global__ void init_cur(const int* __restrict__ rpa, int* __restrict__ cura,
                         const int* __restrict__ brp, int* __restrict__ bcur) {
    int t = threadIdx.x;
    if (t < NAGG) cura[t] = rpa[t];
    if (t < NBKT) bcur[t] = brp[t];
}

// fused per-block counting sort for c2a: LDS hist -> one global atomic per (block,bin)
// to reserve a range -> LDS-cursor scatter
__global__ __launch_bounds__(256) void scatter_c2a(const int* __restrict__ src,
                                                   const int* __restrict__ dst, int E,
                                                   int* __restrict__ cursor,
                                                   int* __restrict__ col) {
    __shared__ int h[NAGG];
    __shared__ int base[NAGG];
    int tid = threadIdx.x;
    int chunk = (E + gridDim.x - 1) / gridDim.x;
    int e0 = blockIdx.x * chunk;
    int e1 = min(E, e0 + chunk);
    for (int i = tid; i < NAGG; i += 256) h[i] = 0;
    __syncthreads();
    for (int e = e0 + tid; e < e1; e += 256) atomicAdd(&h[dst[e]], 1);
    __syncthreads();
    for (int i = tid; i < NAGG; i += 256) {
        int c = h[i];
        base[i] = c ? atomicAdd(&cursor[i], c) : 0;
    }
    __syncthreads();
    for (int e = e0 + tid; e < e1; e += 256) {
        int pos = atomicAdd(&base[dst[e]], 1);
        col[pos] = src[e];
    }
}

// a2c pass 1: bucket by dst>>7; payload packed = (dst&127)<<10 | src  (src < 1024)
__global__ __launch_bounds__(256) void bucket_scatter(const int* __restrict__ src,
                                                      const int* __restrict__ dst, int E,
                                                      int* __restrict__ bcur,
                                                      int* __restrict__ sorted1) {
    __shared__ int h[NBKT];
    __shared__ int base[NBKT];
    int tid = threadIdx.x;
    int chunk = (E + gridDim.x - 1) / gridDim.x;
    int e0 = blockIdx.x * chunk;
    int e1 = min(E, e0 + chunk);
    for (int i = tid; i < NBKT; i += 256) h[i] = 0;
    __syncthreads();
    for (int e = e0 + tid; e < e1; e += 256) atomicAdd(&h[dst[e] >> 7], 1);
    __syncthreads();
    for (int i = tid; i < NBKT; i += 256) {
        int c = h[i];
        base[i] = c ? atomicAdd(&bcur[i], c) : 0;
    }
    __syncthreads();
    for (int e = e0 + tid; e < e1; e += 256) {
        int d = dst[e];
        int pos = atomicAdd(&base[d >> 7], 1);
        sorted1[pos] = ((d & 127) << 10) | src[e];
    }
}

// per-bucket count of low7(dst) -> cnt_c (no global atomics)
__global__ __launch_bounds__(256) void bucket_count(const int* __restrict__ brp,
                                                    const int* __restrict__ sorted1,
                                                    int* __restrict__ cnt_c) {
    __shared__ int h[128];
    int b = blockIdx.x, tid = threadIdx.x;
    if (tid < 128) h[tid] = 0;
    __syncthreads();
    int beg = brp[b], end = brp[b + 1];
    for (int e = beg + tid; e < end; e += 256) atomicAdd(&h[sorted1[e] >> 10], 1);
    __syncthreads();
    if (tid < 128) {
        int c = b * 128 + tid;
        if (c < NCLI) cnt_c[c] = h[tid];
    }
}

// a2c pass 2: per-bucket scatter into final CSR positions (coalesced region per bucket)
__global__ __launch_bounds__(256) void bucket_final(const int* __restrict__ brp,
                                                    const int* __restrict__ sorted1,
                                                    const int* __restrict__ rp_c,
                                                    int* __restrict__ col) {
    __shared__ int cur[128];
    int b = blockIdx.x, tid = threadIdx.x;
    if (tid < 128) {
        int c = b * 128 + tid;
        cur[tid] = (c < NCLI) ? rp_c[c] : 0;
    }
    __syncthreads();
    int beg = brp[b], end = brp[b + 1];
    for (int e = beg + tid; e < end; e += 256) {
        int p = sorted1[e];
        int pos = atomicAdd(&cur[p >> 10], 1);
        col[pos] = p & 1023;
    }
}

// ---------------- layer kernels ----------------

// Y = X @ W for NAGG rows (one block per row, 128 threads)
__global__ void mm_small(const float* __restrict__ X, const float* __restrict__ W,
                         float* __restrict__ Y) {
    __shared__ float xr[D];
    int i = blockIdx.x, j = threadIdx.x;
    xr[j] = X[i * D + j];
    __syncthreads();
    float acc = 0.f;
#pragma unroll 8
    for (int k = 0; k < D; k++) acc += xr[k] * W[k * D + j];
    Y[i * D + j] = acc;
}

// mean over CSR segment of X rows -> out.
// 512 threads = 4 subgroups x 128 lanes, 8-way ILP each, LDS reduce at end.
__global__ __launch_bounds__(512) void mean_agg(const float* __restrict__ X,
                                                const int* __restrict__ rowptr,
                                                const int* __restrict__ col,
                                                float* __restrict__ out) {
    __shared__ int cols[512];
    __shared__ float part[4][D];
    int i = blockIdx.x;
    int tid = threadIdx.x;
    int g = tid >> 7, j = tid & 127;
    int beg = rowptr[i], end = rowptr[i + 1];
    float s0 = 0, s1 = 0, s2 = 0, s3 = 0, s4 = 0, s5 = 0, s6 = 0, s7 = 0;
    for (int base = beg; base < end; base += 512) {
        int m = end - base;
        if (m > 512) m = 512;
        __syncthreads();
        if (tid < m) cols[tid] = col[base + tid];
        __syncthreads();
        int lo = g * 128;
        int hi = min(lo + 128, m);
        int t = lo;
        for (; t + 8 <= hi; t += 8) {
            s0 += X[cols[t + 0] * D + j];
            s1 += X[cols[t + 1] * D + j];
            s2 += X[cols[t + 2] * D + j];
            s3 += X[cols[t + 3] * D + j];
            s4 += X[cols[t + 4] * D + j];
            s5 += X[cols[t + 5] * D + j];
            s6 += X[cols[t + 6] * D + j];
            s7 += X[cols[t + 7] * D + j];
        }
        for (; t < hi; t++) s0 += X[cols[t] * D + j];
    }
    part[g][j] = ((s0 + s1) + (s2 + s3)) + ((s4 + s5) + (s6 + s7));
    __syncthreads();
    if (g == 0) {
        float tot = (part[0][j] + part[1][j]) + (part[2][j] + part[3][j]);
        float c = fmaxf((float)(end - beg), 1.f);
        out[i * D + j] = tot / c;
    }
}

// xa_out = leaky(mean_a @ Wl + xa_old @ Wr + b)   (one block per agg row)
__global__ void new_a_kernel(const float* __restrict__ mean_a, const float* __restrict__ xa_old,
                             const float* __restrict__ Wl, const float* __restrict__ Wr,
                             const float* __restrict__ b, float* __restrict__ xa_out) {
    __shared__ float mr[D], xr[D];
    int i = blockIdx.x, j = threadIdx.x;
    mr[j] = mean_a[i * D + j];
    xr[j] = xa_old[i * D + j];
    __syncthreads();
    float acc = b[j];
#pragma unroll 4
    for (int k = 0; k < D; k++) acc += mr[k] * Wl[k * D + j] + xr[k] * Wr[k * D + j];
    xa_out[i * D + j] = leaky(acc);
}

// Y = X @ W + b, register-tiled: block = 256 threads, 32 rows x 128 cols, 4x4 per thread
__global__ __launch_bounds__(256) void gemm_bias(const float* __restrict__ X,
                                                 const float* __restrict__ W,
                                                 const float* __restrict__ b,
                                                 float* __restrict__ Y, int M) {
    __shared__ float xs[32][D];
    int tid = threadIdx.x;
    int m0 = blockIdx.x * 32;
    for (int idx = tid; idx < 32 * D; idx += 256) {
        int r = idx >> 7, c = idx & 127;
        int row = m0 + r;
        xs[r][c] = (row < M) ? X[row * D + c] : 0.f;
    }
    __syncthreads();
    int jg = tid & 31;
    int cg = tid >> 5;
    float a00 = 0, a01 = 0, a02 = 0, a03 = 0;
    float a10 = 0, a11 = 0, a12 = 0, a13 = 0;
    float a20 = 0, a21 = 0, a22 = 0, a23 = 0;
    float a30 = 0, a31 = 0, a32 = 0, a33 = 0;
#pragma unroll 4
    for (int k = 0; k < D; k++) {
        float4 w = *(const float4*)&W[k * D + jg * 4];
        float x0 = xs[cg * 4 + 0][k];
        float x1 = xs[cg * 4 + 1][k];
        float x2 = xs[cg * 4 + 2][k];
        float x3 = xs[cg * 4 + 3][k];
        a00 += x0 * w.x; a01 += x0 * w.y; a02 += x0 * w.z; a03 += x0 * w.w;
        a10 += x1 * w.x; a11 += x1 * w.y; a12 += x1 * w.z; a13 += x1 * w.w;
        a20 += x2 * w.x; a21 += x2 * w.y; a22 += x2 * w.z; a23 += x2 * w.w;
        a30 += x3 * w.x; a31 += x3 * w.y; a32 += x3 * w.z; a33 += x3 * w.w;
    }
    float4 bv = *(const float4*)&b[jg * 4];
    float4 o;
    int row = m0 + cg * 4;
    if (row + 0 < M) { o = make_float4(a00 + bv.x, a01 + bv.y, a02 + bv.z, a03 + bv.w); *(float4*)&Y[(row + 0) * D + jg * 4] = o; }
    if (row + 1 < M) { o = make_float4(a10 + bv.x, a11 + bv.y, a12 + bv.z, a13 + bv.w); *(float4*)&Y[(row + 1) * D + jg * 4] = o; }
    if (row + 2 < M) { o = make_float4(a20 + bv.x, a21 + bv.y, a22 + bv.z, a23 + bv.w); *(float4*)&Y[(row + 2) * D + jg * 4] = o; }
    if (row + 3 < M) { o = make_float4(a30 + bv.x, a31 + bv.y, a32 + bv.z, a33 + bv.w); *(float4*)&Y[(row + 3) * D + jg * 4] = o; }
}

// Y[i] = leaky(Y[i] + mean_e ya[col[e]])   (one wave per client, 4 clients/block)
__global__ void agg_c_leaky(const float* __restrict__ ya, const int* __restrict__ rowptr,
                            const int* __restrict__ col, float* __restrict__ Y) {
    int lane = threadIdx.x & 63;
    int gid = blockIdx.x * 4 + (threadIdx.x >> 6);
    if (gid >= NCLI) return;
    int beg = rowptr[gid], end = rowptr[gid + 1];
    float s0 = 0.f, s1 = 0.f, s2 = 0.f, s3 = 0.f;
    int e = beg;
    for (; e + 2 <= end; e += 2) {
        int r0 = col[e], r1 = col[e + 1];
        s0 += ya[r0 * D + lane];
        s1 += ya[r0 * D + 64 + lane];
        s2 += ya[r1 * D + lane];
        s3 += ya[r1 * D + 64 + lane];
    }
    if (e < end) {
        int r0 = col[e];
        s0 += ya[r0 * D + lane];
        s1 += ya[r0 * D + 64 + lane];
    }
    float c = fmaxf((float)(end - beg), 1.f);
    int idx = gid * D + lane;
    Y[idx] = leaky(Y[idx] + (s0 + s2) / c);
    Y[idx + 64] = leaky(Y[idx + 64] + (s1 + s3) / c);
}

// out[i] = xc[i] . W_lin + b_lin  (one wave per client)
__global__ void out_kernel(const float* __restrict__ xc, const float* __restrict__ Wlin,
                           const float* __restrict__ blin, float* __restrict__ out) {
    int lane = threadIdx.x & 63;
    int gid = blockIdx.x * 4 + (threadIdx.x >> 6);
    if (gid >= NCLI) return;
    float v = xc[gid * D + lane] * Wlin[lane] + xc[gid * D + 64 + lane] * Wlin[64 + lane];
#pragma unroll
    for (int off = 32; off > 0; off >>= 1) v += __shfl_down(v, off);
    if (lane == 0) out[gid] = v + blin[0];
}

extern "C" void kernel_launch(void* const* d_in, const int* in_sizes, int n_in,
                              void* d_out, int out_size, void* d_ws, size_t ws_size,
                              hipStream_t stream) {
    const float* x_clients = (const float*)d_in[0];
    const float* x_agg     = (const float*)d_in[1];
    const int*   c2a_src   = (const int*)d_in[2];
    const int*   c2a_dst   = (const int*)d_in[3];
    const int*   a2c_src   = (const int*)d_in[4];
    const int*   a2c_dst   = (const int*)d_in[5];
    const float* Wl_c2a    = (const float*)d_in[6];
    const float* Wr_c2a    = (const float*)d_in[7];
    const float* b_c2a     = (const float*)d_in[8];
    const float* Wl_a2c    = (const float*)d_in[9];
    const float* Wr_a2c    = (const float*)d_in[10];
    const float* b_a2c     = (const float*)d_in[11];
    const float* W_lin     = (const float*)d_in[12];
    const float* b_lin     = (const float*)d_in[13];
    float* out = (float*)d_out;
    const int E = in_sizes[2];

    char* p = (char*)d_ws;
    auto alloc = [&](size_t bytes) {
        char* r = p;
        p += (bytes + 255) & ~(size_t)255;
        return r;
    };
    float* xcA = (float*)alloc(sizeof(float) * NCLI * D);
    float* xcB = (float*)alloc(sizeof(float) * NCLI * D);
    float* xa  = (float*)alloc(sizeof(float) * NAGG * D);
    float* ya  = (float*)alloc(sizeof(float) * NAGG * D);
    float* ma  = (float*)alloc(sizeof(float) * NAGG * D);
    int* cnt_a = (int*)alloc(sizeof(int) * NAGG);
    int* rp_a  = (int*)alloc(sizeof(int) * (NAGG + 1));
    int* cur_a = (int*)alloc(sizeof(int) * NAGG);
    int* bcnt  = (int*)alloc(sizeof(int) * NBKT);
    int* brp   = (int*)alloc(sizeof(int) * (NBKT + 1));
    int* bcur  = (int*)alloc(sizeof(int) * NBKT);
    int* cnt_c = (int*)alloc(sizeof(int) * NCLI);
    int* rp_c  = (int*)alloc(sizeof(int) * (NCLI + 1));
    int* bsums = (int*)alloc(sizeof(int) * 128);
    int* boffs = (int*)alloc(sizeof(int) * 128);
    int* col_c2a = (int*)alloc(sizeof(int) * E);
    int* col_a2c = (int*)alloc(sizeof(int) * E);
    // sorted1 aliases xcA: lifetime disjoint (CSR build completes before layer-0 gemm writes xcA)
    int* sorted1 = (int*)xcA;

    hipMemsetAsync(cnt_a, 0, sizeof(int) * NAGG, stream);
    hipMemsetAsync(bcnt, 0, sizeof(int) * NBKT, stream);

    hist_small<<<256, 256, 0, stream>>>(c2a_dst, E, cnt_a);
    bucket_hist<<<256, 256, 0, stream>>>(a2c_dst, E, bcnt);
    scan_1024<<<1, 1024, 0, stream>>>(cnt_a, NAGG, rp_a);
    scan_1024<<<1, 1024, 0, stream>>>(bcnt, NBKT, brp);
    init_cur<<<1, 1024, 0, stream>>>(rp_a, cur_a, brp, bcur);
    scatter_c2a<<<256, 256, 0, stream>>>(c2a_src, c2a_dst, E, cur_a, col_c2a);
    bucket_scatter<<<256, 256, 0, stream>>>(a2c_src, a2c_dst, E, bcur, sorted1);
    bucket_count<<<NBKT, 256, 0, stream>>>(brp, sorted1, cnt_c);
    int nb = (NCLI + 1023) / 1024;  // 98
    scan_chunk<<<nb, 1024, 0, stream>>>(cnt_c, NCLI, rp_c, bsums);
    scan_bsums<<<1, 128, 0, stream>>>(bsums, nb, boffs);
    scan_apply<<<nb, 1024, 0, stream>>>(NCLI, rp_c, boffs);
    bucket_final<<<NBKT, 256, 0, stream>>>(brp, sorted1, rp_c, col_a2c);

    const float* xc_old = x_clients;
    const float* xa_old = x_agg;
    float* xc_bufs[2] = {xcA, xcB};
    for (int l = 0; l < NLAYER; l++) {
        float* xc_new = xc_bufs[l & 1];
        // ya = xa_old @ Wl_a2c[l]   (folds mean_c @ Wl into aggregation of ya rows)
        mm_small<<<NAGG, D, 0, stream>>>(xa_old, Wl_a2c + l * D * D, ya);
        // mean_a over c2a edges of xc_old
        mean_agg<<<NAGG, 512, 0, stream>>>(xc_old, rp_a, col_c2a, ma);
        // xa = leaky(mean_a @ Wl_c2a + xa_old @ Wr_c2a + b_c2a)
        new_a_kernel<<<NAGG, D, 0, stream>>>(ma, xa_old, Wl_c2a + l * D * D, Wr_c2a + l * D * D,
                                             b_c2a + l * D, xa);
        // xc_new = xc_old @ Wr_a2c + b_a2c
        gemm_bias<<<(NCLI + 31) / 32, 256, 0, stream>>>(xc_old, Wr_a2c + l * D * D, b_a2c + l * D,
                                                        xc_new, NCLI);
        // xc_new = leaky(xc_new + mean_e ya[src])
        agg_c_leaky<<<(NCLI + 3) / 4, 256, 0, stream>>>(ya, rp_c, col_a2c, xc_new);
        xc_old = xc_new;
        xa_old = xa;
    }
    out_kernel<<<(NCLI + 3) / 4, 256, 0, stream>>>(xc_old, W_lin, b_lin, out);
}

// Round 3
// 923.975 us; speedup vs baseline: 1.8867x; 1.1776x over previous
//
#include <hip/hip_runtime.h>

#define D      128
#define NCLI   100000
#define NAGG   1000
#define NLAYER 3
#define NBKT   782   // ceil(NCLI/128)

static __device__ __forceinline__ float leaky(float x) { return x >= 0.f ? x : 0.1f * x; }

// ---- bf16 pack/unpack (RNE) ----
static __device__ __forceinline__ unsigned bf16_rn(float f) {
    unsigned u = __float_as_uint(f);
    return (u + 0x7fffu + ((u >> 16) & 1u)) >> 16;
}
static __device__ __forceinline__ unsigned pack_bf2(float lo, float hi) {
    return bf16_rn(lo) | (bf16_rn(hi) << 16);
}
static __device__ __forceinline__ float bf_lo(unsigned v) { return __uint_as_float(v << 16); }
static __device__ __forceinline__ float bf_hi(unsigned v) { return __uint_as_float(v & 0xffff0000u); }

// ---------------- CSR build ----------------

__global__ __launch_bounds__(256) void hist_small(const int* __restrict__ dst, int E,
                                                  int* __restrict__ cnt) {
    __shared__ int h[NAGG];
    for (int i = threadIdx.x; i < NAGG; i += 256) h[i] = 0;
    __syncthreads();
    int stride = gridDim.x * 256;
    for (int e = blockIdx.x * 256 + threadIdx.x; e < E; e += stride)
        atomicAdd(&h[dst[e]], 1);
    __syncthreads();
    for (int i = threadIdx.x; i < NAGG; i += 256)
        if (h[i]) atomicAdd(&cnt[i], h[i]);
}

__global__ __launch_bounds__(256) void bucket_hist(const int* __restrict__ dst, int E,
                                                   int* __restrict__ cnt) {
    __shared__ int h[NBKT];
    for (int i = threadIdx.x; i < NBKT; i += 256) h[i] = 0;
    __syncthreads();
    int stride = gridDim.x * 256;
    for (int e = blockIdx.x * 256 + threadIdx.x; e < E; e += stride)
        atomicAdd(&h[dst[e] >> 7], 1);
    __syncthreads();
    for (int i = threadIdx.x; i < NBKT; i += 256)
        if (h[i]) atomicAdd(&cnt[i], h[i]);
}

__global__ void scan_1024(const int* __restrict__ cnt, int n, int* __restrict__ rowptr) {
    __shared__ int sh[1024];
    int t = threadIdx.x;
    int v = (t < n) ? cnt[t] : 0;
    sh[t] = v;
    __syncthreads();
    for (int off = 1; off < 1024; off <<= 1) {
        int x = (t >= off) ? sh[t - off] : 0;
        __syncthreads();
        sh[t] += x;
        __syncthreads();
    }
    if (t == 0) rowptr[0] = 0;
    if (t < n) rowptr[t + 1] = sh[t];
}

__global__ void scan_chunk(const int* __restrict__ cnt, int n, int* __restrict__ rowptr,
                           int* __restrict__ bsums) {
    __shared__ int sh[1024];
    int t = threadIdx.x;
    int i = blockIdx.x * 1024 + t;
    int v = (i < n) ? cnt[i] : 0;
    sh[t] = v;
    __syncthreads();
    for (int off = 1; off < 1024; off <<= 1) {
        int x = (t >= off) ? sh[t - off] : 0;
        __syncthreads();
        sh[t] += x;
        __syncthreads();
    }
    if (i < n) rowptr[i + 1] = sh[t];
    if (t == 1023) bsums[blockIdx.x] = sh[t];
}

__global__ void scan_bsums(const int* __restrict__ bsums, int nb, int* __restrict__ boffs) {
    __shared__ int sh[128];
    int t = threadIdx.x;
    int v = (t < nb) ? bsums[t] : 0;
    sh[t] = v;
    __syncthreads();
    for (int off = 1; off < 128; off <<= 1) {
        int x = (t >= off) ? sh[t - off] : 0;
        __syncthreads();
        sh[t] += x;
        __syncthreads();
    }
    if (t < nb) boffs[t] = sh[t] - v;  // exclusive
}

__global__ void scan_apply(int n, int* __restrict__ rowptr, const int* __restrict__ boffs) {
    int i = blockIdx.x * 1024 + threadIdx.x;
    if (i < n) rowptr[i + 1] += boffs[blockIdx.x];
    if (i == 0) rowptr[0] = 0;
}

__global__ void init_cur(const int* __restrict__ rpa, int* __restrict__ cura,
                         const int* __restrict__ brp, int* __restrict__ bcur) {
    int t = threadIdx.x;
    if (t < NAGG) cura[t] = rpa[t];
    if (t < NBKT) bcur[t] = brp[t];
}

__global__ __launch_bounds__(256) void scatter_c2a(const int* __restrict__ src,
                                                   const int* __restrict__ dst, int E,
                                                   int* __restrict__ cursor,
                                                   int* __restrict__ col) {
    __shared__ int h[NAGG];
    __shared__ int base[NAGG];
    int tid = threadIdx.x;
    int chunk = (E + gridDim.x - 1) / gridDim.x;
    int e0 = blockIdx.x * chunk;
    int e1 = min(E, e0 + chunk);
    for (int i = tid; i < NAGG; i += 256) h[i] = 0;
    __syncthreads();
    for (int e = e0 + tid; e < e1; e += 256) atomicAdd(&h[dst[e]], 1);
    __syncthreads();
    for (int i = tid; i < NAGG; i += 256) {
        int c = h[i];
        base[i] = c ? atomicAdd(&cursor[i], c) : 0;
    }
    __syncthreads();
    for (int e = e0 + tid; e < e1; e += 256) {
        int pos = atomicAdd(&base[dst[e]], 1);
        col[pos] = src[e];
    }
}

__global__ __launch_bounds__(256) void bucket_scatter(const int* __restrict__ src,
                                                      const int* __restrict__ dst, int E,
                                                      int* __restrict__ bcur,
                                                      int* __restrict__ sorted1) {
    __shared__ int h[NBKT];
    __shared__ int base[NBKT];
    int tid = threadIdx.x;
    int chunk = (E + gridDim.x - 1) / gridDim.x;
    int e0 = blockIdx.x * chunk;
    int e1 = min(E, e0 + chunk);
    for (int i = tid; i < NBKT; i += 256) h[i] = 0;
    __syncthreads();
    for (int e = e0 + tid; e < e1; e += 256) atomicAdd(&h[dst[e] >> 7], 1);
    __syncthreads();
    for (int i = tid; i < NBKT; i += 256) {
        int c = h[i];
        base[i] = c ? atomicAdd(&bcur[i], c) : 0;
    }
    __syncthreads();
    for (int e = e0 + tid; e < e1; e += 256) {
        int d = dst[e];
        int pos = atomicAdd(&base[d >> 7], 1);
        sorted1[pos] = ((d & 127) << 10) | src[e];
    }
}

__global__ __launch_bounds__(256) void bucket_count(const int* __restrict__ brp,
                                                    const int* __restrict__ sorted1,
                                                    int* __restrict__ cnt_c) {
    __shared__ int h[128];
    int b = blockIdx.x, tid = threadIdx.x;
    if (tid < 128) h[tid] = 0;
    __syncthreads();
    int beg = brp[b], end = brp[b + 1];
    for (int e = beg + tid; e < end; e += 256) atomicAdd(&h[sorted1[e] >> 10], 1);
    __syncthreads();
    if (tid < 128) {
        int c = b * 128 + tid;
        if (c < NCLI) cnt_c[c] = h[tid];
    }
}

__global__ __launch_bounds__(256) void bucket_final(const int* __restrict__ brp,
                                                    const int* __restrict__ sorted1,
                                                    const int* __restrict__ rp_c,
                                                    int* __restrict__ col) {
    __shared__ int cur[128];
    int b = blockIdx.x, tid = threadIdx.x;
    if (tid < 128) {
        int c = b * 128 + tid;
        cur[tid] = (c < NCLI) ? rp_c[c] : 0;
    }
    __syncthreads();
    int beg = brp[b], end = brp[b + 1];
    for (int e = beg + tid; e < end; e += 256) {
        int p = sorted1[e];
        int pos = atomicAdd(&cur[p >> 10], 1);
        col[pos] = p & 1023;
    }
}

// ---------------- layer kernels ----------------

// pack f32 -> bf16x2 shadow of x_clients
__global__ __launch_bounds__(256) void cvt_x(const float4* __restrict__ X4,
                                             uint2* __restrict__ out, int n4) {
    int t = blockIdx.x * 256 + threadIdx.x;
    if (t >= n4) return;
    float4 f = X4[t];
    out[t] = make_uint2(pack_bf2(f.x, f.y), pack_bf2(f.z, f.w));
}

// ya_bf = bf16(xa_old @ Wl) for NAGG rows (one block per row, 128 threads)
__global__ void mm_small_bf(const float* __restrict__ X, const float* __restrict__ W,
                            unsigned short* __restrict__ Ybf) {
    __shared__ float xr[D];
    int i = blockIdx.x, j = threadIdx.x;
    xr[j] = X[i * D + j];
    __syncthreads();
    float acc = 0.f;
#pragma unroll 8
    for (int k = 0; k < D; k++) acc += xr[k] * W[k * D + j];
    Ybf[i * D + j] = (unsigned short)bf16_rn(acc);
}

// mean over CSR segment of bf16x2 rows -> f32 out.
// 512 threads = 8 groups x 64 lanes; lane covers cols {2l, 2l+1}; 8-way ILP.
__global__ __launch_bounds__(512) void mean_agg_bf(const unsigned* __restrict__ tbl,
                                                   const int* __restrict__ rowptr,
                                                   const int* __restrict__ col,
                                                   float* __restrict__ out) {
    __shared__ int cols[512];
    __shared__ float part[8][D];
    int i = blockIdx.x, tid = threadIdx.x;
    int g = tid >> 6, l = tid & 63;
    int beg = rowptr[i], end = rowptr[i + 1];
    float x0 = 0, y0 = 0, x1 = 0, y1 = 0, x2 = 0, y2 = 0, x3 = 0, y3 = 0;
    float x4 = 0, y4 = 0, x5 = 0, y5 = 0, x6 = 0, y6 = 0, x7 = 0, y7 = 0;
    for (int base = beg; base < end; base += 512) {
        int m = end - base;
        if (m > 512) m = 512;
        __syncthreads();
        if (tid < m) cols[tid] = col[base + tid];
        __syncthreads();
        int lo = g * 64;
        int hi = min(lo + 64, m);
        int t = lo;
        for (; t + 8 <= hi; t += 8) {
            unsigned v0 = tbl[(cols[t + 0] << 6) + l];
            unsigned v1 = tbl[(cols[t + 1] << 6) + l];
            unsigned v2 = tbl[(cols[t + 2] << 6) + l];
            unsigned v3 = tbl[(cols[t + 3] << 6) + l];
            unsigned v4 = tbl[(cols[t + 4] << 6) + l];
            unsigned v5 = tbl[(cols[t + 5] << 6) + l];
            unsigned v6 = tbl[(cols[t + 6] << 6) + l];
            unsigned v7 = tbl[(cols[t + 7] << 6) + l];
            x0 += bf_lo(v0); y0 += bf_hi(v0);
            x1 += bf_lo(v1); y1 += bf_hi(v1);
            x2 += bf_lo(v2); y2 += bf_hi(v2);
            x3 += bf_lo(v3); y3 += bf_hi(v3);
            x4 += bf_lo(v4); y4 += bf_hi(v4);
            x5 += bf_lo(v5); y5 += bf_hi(v5);
            x6 += bf_lo(v6); y6 += bf_hi(v6);
            x7 += bf_lo(v7); y7 += bf_hi(v7);
        }
        for (; t < hi; t++) {
            unsigned v = tbl[(cols[t] << 6) + l];
            x0 += bf_lo(v); y0 += bf_hi(v);
        }
    }
    part[g][2 * l]     = ((x0 + x1) + (x2 + x3)) + ((x4 + x5) + (x6 + x7));
    part[g][2 * l + 1] = ((y0 + y1) + (y2 + y3)) + ((y4 + y5) + (y6 + y7));
    __syncthreads();
    if (tid < D) {
        float tot = 0.f;
#pragma unroll
        for (int gg = 0; gg < 8; gg++) tot += part[gg][tid];
        out[i * D + tid] = tot / fmaxf((float)(end - beg), 1.f);
    }
}

// xa_out = leaky(mean_a @ Wl + xa_old @ Wr + b); may run in place (xa_out == xa_old)
__global__ void new_a_kernel(const float* __restrict__ mean_a, const float* xa_old,
                             const float* __restrict__ Wl, const float* __restrict__ Wr,
                             const float* __restrict__ b, float* xa_out) {
    __shared__ float mr[D], xr[D];
    int i = blockIdx.x, j = threadIdx.x;
    mr[j] = mean_a[i * D + j];
    xr[j] = xa_old[i * D + j];
    __syncthreads();
    float acc = b[j];
#pragma unroll 4
    for (int k = 0; k < D; k++) acc += mr[k] * Wl[k * D + j] + xr[k] * Wr[k * D + j];
    xa_out[i * D + j] = leaky(acc);
}

// Y = X @ W + b; row-local => safe in place (Y == X)
__global__ __launch_bounds__(256) void gemm_bias(const float* X, const float* __restrict__ W,
                                                 const float* __restrict__ b, float* Y, int M) {
    __shared__ float xs[32][D];
    int tid = threadIdx.x;
    int m0 = blockIdx.x * 32;
    for (int idx = tid; idx < 32 * D; idx += 256) {
        int r = idx >> 7, c = idx & 127;
        int row = m0 + r;
        xs[r][c] = (row < M) ? X[row * D + c] : 0.f;
    }
    __syncthreads();
    int jg = tid & 31;
    int cg = tid >> 5;
    float a00 = 0, a01 = 0, a02 = 0, a03 = 0;
    float a10 = 0, a11 = 0, a12 = 0, a13 = 0;
    float a20 = 0, a21 = 0, a22 = 0, a23 = 0;
    float a30 = 0, a31 = 0, a32 = 0, a33 = 0;
#pragma unroll 4
    for (int k = 0; k < D; k++) {
        float4 w = *(const float4*)&W[k * D + jg * 4];
        float x0 = xs[cg * 4 + 0][k];
        float x1 = xs[cg * 4 + 1][k];
        float x2 = xs[cg * 4 + 2][k];
        float x3 = xs[cg * 4 + 3][k];
        a00 += x0 * w.x; a01 += x0 * w.y; a02 += x0 * w.z; a03 += x0 * w.w;
        a10 += x1 * w.x; a11 += x1 * w.y; a12 += x1 * w.z; a13 += x1 * w.w;
        a20 += x2 * w.x; a21 += x2 * w.y; a22 += x2 * w.z; a23 += x2 * w.w;
        a30 += x3 * w.x; a31 += x3 * w.y; a32 += x3 * w.z; a33 += x3 * w.w;
    }
    float4 bv = *(const float4*)&b[jg * 4];
    float4 o;
    int row = m0 + cg * 4;
    if (row + 0 < M) { o = make_float4(a00 + bv.x, a01 + bv.y, a02 + bv.z, a03 + bv.w); *(float4*)&Y[(row + 0) * D + jg * 4] = o; }
    if (row + 1 < M) { o = make_float4(a10 + bv.x, a11 + bv.y, a12 + bv.z, a13 + bv.w); *(float4*)&Y[(row + 1) * D + jg * 4] = o; }
    if (row + 2 < M) { o = make_float4(a20 + bv.x, a21 + bv.y, a22 + bv.z, a23 + bv.w); *(float4*)&Y[(row + 2) * D + jg * 4] = o; }
    if (row + 3 < M) { o = make_float4(a30 + bv.x, a31 + bv.y, a32 + bv.z, a33 + bv.w); *(float4*)&Y[(row + 3) * D + jg * 4] = o; }
}

// xc = leaky(Y + mean_e ya_bf[col[e]]); LAST=0: write f32 + bf16 shadow;
// LAST=1: fuse final linear head, write out only. One wave per client, 4/block.
template <int LAST>
__global__ __launch_bounds__(256) void agg_c_bf(const unsigned* __restrict__ ya,
                                                const int* __restrict__ rowptr,
                                                const int* __restrict__ col, float* Y,
                                                unsigned* __restrict__ xbf,
                                                const float* __restrict__ Wlin,
                                                const float* __restrict__ blin,
                                                float* __restrict__ out) {
    int l = threadIdx.x & 63;
    int gid = blockIdx.x * 4 + (threadIdx.x >> 6);
    if (gid >= NCLI) return;
    int beg = rowptr[gid], end = rowptr[gid + 1];
    float mx = 0, my = 0, nx = 0, ny = 0;
    int e = beg;
    for (; e + 2 <= end; e += 2) {
        unsigned v0 = ya[(col[e] << 6) + l];
        unsigned v1 = ya[(col[e + 1] << 6) + l];
        mx += bf_lo(v0); my += bf_hi(v0);
        nx += bf_lo(v1); ny += bf_hi(v1);
    }
    if (e < end) {
        unsigned v0 = ya[(col[e] << 6) + l];
        mx += bf_lo(v0); my += bf_hi(v0);
    }
    float inv = 1.f / fmaxf((float)(end - beg), 1.f);
    float2 yv = *(float2*)&Y[gid * D + 2 * l];
    float r0 = leaky(yv.x + (mx + nx) * inv);
    float r1 = leaky(yv.y + (my + ny) * inv);
    if (LAST) {
        float2 w = *(const float2*)&Wlin[2 * l];
        float v = r0 * w.x + r1 * w.y;
#pragma unroll
        for (int off = 32; off > 0; off >>= 1) v += __shfl_down(v, off);
        if (l == 0) out[gid] = v + blin[0];
    } else {
        *(float2*)&Y[gid * D + 2 * l] = make_float2(r0, r1);
        xbf[(gid << 6) + l] = pack_bf2(r0, r1);
    }
}

extern "C" void kernel_launch(void* const* d_in, const int* in_sizes, int n_in,
                              void* d_out, int out_size, void* d_ws, size_t ws_size,
                              hipStream_t stream) {
    const float* x_clients = (const float*)d_in[0];
    const float* x_agg     = (const float*)d_in[1];
    const int*   c2a_src   = (const int*)d_in[2];
    const int*   c2a_dst   = (const int*)d_in[3];
    const int*   a2c_src   = (const int*)d_in[4];
    const int*   a2c_dst   = (const int*)d_in[5];
    const float* Wl_c2a    = (const float*)d_in[6];
    const float* Wr_c2a    = (const float*)d_in[7];
    const float* b_c2a     = (const float*)d_in[8];
    const float* Wl_a2c    = (const float*)d_in[9];
    const float* Wr_a2c    = (const float*)d_in[10];
    const float* b_a2c     = (const float*)d_in[11];
    const float* W_lin     = (const float*)d_in[12];
    const float* b_lin     = (const float*)d_in[13];
    float* out = (float*)d_out;
    const int E = in_sizes[2];

    char* p = (char*)d_ws;
    auto alloc = [&](size_t bytes) {
        char* r = p;
        p += (bytes + 255) & ~(size_t)255;
        return r;
    };
    float*    xcA   = (float*)alloc(sizeof(float) * NCLI * D);      // f32 master xc
    unsigned* xcbf  = (unsigned*)alloc(sizeof(unsigned) * NCLI * 64);  // bf16x2 shadow
    float*    xa    = (float*)alloc(sizeof(float) * NAGG * D);
    unsigned short* ya_bf = (unsigned short*)alloc(sizeof(unsigned short) * NAGG * D);
    float*    ma    = (float*)alloc(sizeof(float) * NAGG * D);
    int* cnt_a = (int*)alloc(sizeof(int) * NAGG);
    int* rp_a  = (int*)alloc(sizeof(int) * (NAGG + 1));
    int* cur_a = (int*)alloc(sizeof(int) * NAGG);
    int* bcnt  = (int*)alloc(sizeof(int) * NBKT);
    int* brp   = (int*)alloc(sizeof(int) * (NBKT + 1));
    int* bcur  = (int*)alloc(sizeof(int) * NBKT);
    int* cnt_c = (int*)alloc(sizeof(int) * NCLI);
    int* rp_c  = (int*)alloc(sizeof(int) * (NCLI + 1));
    int* bsums = (int*)alloc(sizeof(int) * 128);
    int* boffs = (int*)alloc(sizeof(int) * 128);
    int* col_c2a = (int*)alloc(sizeof(int) * E);
    int* col_a2c = (int*)alloc(sizeof(int) * E);
    // sorted1 aliases xcA: lifetime disjoint (CSR build completes before layer-0 gemm writes xcA)
    int* sorted1 = (int*)xcA;

    hipMemsetAsync(cnt_a, 0, sizeof(int) * NAGG, stream);
    hipMemsetAsync(bcnt, 0, sizeof(int) * NBKT, stream);

    // bf16 shadow of layer-0 client features
    cvt_x<<<(NCLI * D / 4 + 255) / 256, 256, 0, stream>>>((const float4*)x_clients,
                                                          (uint2*)xcbf, NCLI * D / 4);

    hist_small<<<256, 256, 0, stream>>>(c2a_dst, E, cnt_a);
    bucket_hist<<<256, 256, 0, stream>>>(a2c_dst, E, bcnt);
    scan_1024<<<1, 1024, 0, stream>>>(cnt_a, NAGG, rp_a);
    scan_1024<<<1, 1024, 0, stream>>>(bcnt, NBKT, brp);
    init_cur<<<1, 1024, 0, stream>>>(rp_a, cur_a, brp, bcur);
    scatter_c2a<<<256, 256, 0, stream>>>(c2a_src, c2a_dst, E, cur_a, col_c2a);
    bucket_scatter<<<256, 256, 0, stream>>>(a2c_src, a2c_dst, E, bcur, sorted1);
    bucket_count<<<NBKT, 256, 0, stream>>>(brp, sorted1, cnt_c);
    int nb = (NCLI + 1023) / 1024;  // 98
    scan_chunk<<<nb, 1024, 0, stream>>>(cnt_c, NCLI, rp_c, bsums);
    scan_bsums<<<1, 128, 0, stream>>>(bsums, nb, boffs);
    scan_apply<<<nb, 1024, 0, stream>>>(NCLI, rp_c, boffs);
    bucket_final<<<NBKT, 256, 0, stream>>>(brp, sorted1, rp_c, col_a2c);

    const float* xc_old = x_clients;
    const float* xa_old = x_agg;
    for (int l = 0; l < NLAYER; l++) {
        // ya_bf = bf16(xa_old @ Wl_a2c[l])  (folds mean_c @ Wl into gather of ya rows)
        mm_small_bf<<<NAGG, D, 0, stream>>>(xa_old, Wl_a2c + l * D * D, ya_bf);
        // mean_a over c2a edges of bf16 shadow
        mean_agg_bf<<<NAGG, 512, 0, stream>>>(xcbf, rp_a, col_c2a, ma);
        // xa = leaky(mean_a @ Wl_c2a + xa_old @ Wr_c2a + b_c2a)  (in place for l>0)
        new_a_kernel<<<NAGG, D, 0, stream>>>(ma, xa_old, Wl_c2a + l * D * D, Wr_c2a + l * D * D,
                                             b_c2a + l * D, xa);
        // xcA = xc_old @ Wr_a2c + b_a2c  (in place for l>0; row-local)
        gemm_bias<<<(NCLI + 31) / 32, 256, 0, stream>>>(xc_old, Wr_a2c + l * D * D, b_a2c + l * D,
                                                        xcA, NCLI);
        // xcA = leaky(xcA + mean ya); last layer fuses the linear head
        if (l < NLAYER - 1) {
            agg_c_bf<0><<<(NCLI + 3) / 4, 256, 0, stream>>>(ya_bf ? (const unsigned*)ya_bf : nullptr,
                                                            rp_c, col_a2c, xcA, xcbf,
                                                            nullptr, nullptr, nullptr);
        } else {
            agg_c_bf<1><<<(NCLI + 3) / 4, 256, 0, stream>>>((const unsigned*)ya_bf, rp_c, col_a2c,
                                                            xcA, nullptr, W_lin, b_lin, out);
        }
        xc_old = xcA;
        xa_old = xa;
    }
}

// Round 4
// 813.465 us; speedup vs baseline: 2.1430x; 1.1359x over previous
//
#include <hip/hip_runtime.h>

#define D      128
#define NCLI   100000
#define NAGG   1000
#define NLAYER 3
#define NBKT   782   // ceil(NCLI/128)

static __device__ __forceinline__ float leaky(float x) { return x >= 0.f ? x : 0.1f * x; }

// ---- bf16 pack/unpack (RNE) ----
static __device__ __forceinline__ unsigned bf16_rn(float f) {
    unsigned u = __float_as_uint(f);
    return (u + 0x7fffu + ((u >> 16) & 1u)) >> 16;
}
static __device__ __forceinline__ unsigned pack_bf2(float lo, float hi) {
    return bf16_rn(lo) | (bf16_rn(hi) << 16);
}
static __device__ __forceinline__ float bf_lo(unsigned v) { return __uint_as_float(v << 16); }
static __device__ __forceinline__ float bf_hi(unsigned v) { return __uint_as_float(v & 0xffff0000u); }

// ---------------- CSR build ----------------

// one pass builds both histograms: cnt_a over c2a_dst (NAGG bins), bcnt over a2c_dst>>7 (NBKT)
__global__ __launch_bounds__(256) void hist_both(const int* __restrict__ c2a_dst,
                                                 const int* __restrict__ a2c_dst, int E,
                                                 int* __restrict__ cnt_a, int* __restrict__ bcnt) {
    __shared__ int h[NAGG + NBKT];
    for (int i = threadIdx.x; i < NAGG + NBKT; i += 256) h[i] = 0;
    __syncthreads();
    int stride = gridDim.x * 256;
    for (int e = blockIdx.x * 256 + threadIdx.x; e < E; e += stride) {
        atomicAdd(&h[c2a_dst[e]], 1);
        atomicAdd(&h[NAGG + (a2c_dst[e] >> 7)], 1);
    }
    __syncthreads();
    for (int i = threadIdx.x; i < NAGG; i += 256)
        if (h[i]) atomicAdd(&cnt_a[i], h[i]);
    for (int i = threadIdx.x; i < NBKT; i += 256)
        if (h[NAGG + i]) atomicAdd(&bcnt[i], h[NAGG + i]);
}

// block 0: scan cnt_a -> rp_a + cur_a; block 1: scan bcnt -> brp + bcur
__global__ void scan_both(const int* __restrict__ cnt_a, int* __restrict__ rp_a,
                          int* __restrict__ cur_a, const int* __restrict__ bcnt,
                          int* __restrict__ brp, int* __restrict__ bcur) {
    __shared__ int sh[1024];
    const int* cnt;
    int *rp, *cur, n;
    if (blockIdx.x == 0) { cnt = cnt_a; rp = rp_a; cur = cur_a; n = NAGG; }
    else                 { cnt = bcnt;  rp = brp;  cur = bcur;  n = NBKT; }
    int t = threadIdx.x;
    int v = (t < n) ? cnt[t] : 0;
    sh[t] = v;
    __syncthreads();
    for (int off = 1; off < 1024; off <<= 1) {
        int x = (t >= off) ? sh[t - off] : 0;
        __syncthreads();
        sh[t] += x;
        __syncthreads();
    }
    if (t == 0) { rp[0] = 0; cur[0] = 0; }
    if (t < n) {
        rp[t + 1] = sh[t];
        if (t + 1 < n) cur[t + 1] = sh[t];
    }
}

__global__ __launch_bounds__(256) void scatter_c2a(const int* __restrict__ src,
                                                   const int* __restrict__ dst, int E,
                                                   int* __restrict__ cursor,
                                                   int* __restrict__ col) {
    __shared__ int h[NAGG];
    __shared__ int base[NAGG];
    int tid = threadIdx.x;
    int chunk = (E + gridDim.x - 1) / gridDim.x;
    int e0 = blockIdx.x * chunk;
    int e1 = min(E, e0 + chunk);
    for (int i = tid; i < NAGG; i += 256) h[i] = 0;
    __syncthreads();
    for (int e = e0 + tid; e < e1; e += 256) atomicAdd(&h[dst[e]], 1);
    __syncthreads();
    for (int i = tid; i < NAGG; i += 256) {
        int c = h[i];
        base[i] = c ? atomicAdd(&cursor[i], c) : 0;
    }
    __syncthreads();
    for (int e = e0 + tid; e < e1; e += 256) {
        int pos = atomicAdd(&base[dst[e]], 1);
        col[pos] = src[e];
    }
}

__global__ __launch_bounds__(256) void bucket_scatter(const int* __restrict__ src,
                                                      const int* __restrict__ dst, int E,
                                                      int* __restrict__ bcur,
                                                      int* __restrict__ sorted1) {
    __shared__ int h[NBKT];
    __shared__ int base[NBKT];
    int tid = threadIdx.x;
    int chunk = (E + gridDim.x - 1) / gridDim.x;
    int e0 = blockIdx.x * chunk;
    int e1 = min(E, e0 + chunk);
    for (int i = tid; i < NBKT; i += 256) h[i] = 0;
    __syncthreads();
    for (int e = e0 + tid; e < e1; e += 256) atomicAdd(&h[dst[e] >> 7], 1);
    __syncthreads();
    for (int i = tid; i < NBKT; i += 256) {
        int c = h[i];
        base[i] = c ? atomicAdd(&bcur[i], c) : 0;
    }
    __syncthreads();
    for (int e = e0 + tid; e < e1; e += 256) {
        int d = dst[e];
        int pos = atomicAdd(&base[d >> 7], 1);
        sorted1[pos] = ((d & 127) << 10) | src[e];
    }
}

// per bucket: LDS hist(128) -> LDS exclusive scan -> write rp_c -> LDS-cursor scatter.
// bucket-major + client-major-within-bucket layout makes rp_c globally consistent
// (bucket b's first client starts exactly at brp[b]) -- no global scan needed.
__global__ __launch_bounds__(256) void bucket_csr(const int* __restrict__ brp,
                                                  const int* __restrict__ sorted1,
                                                  int* __restrict__ rp_c,
                                                  int* __restrict__ col) {
    __shared__ int h[128], cur[128];
    int b = blockIdx.x, tid = threadIdx.x;
    if (tid < 128) h[tid] = 0;
    __syncthreads();
    int beg = brp[b], end = brp[b + 1];
    for (int e = beg + tid; e < end; e += 256) atomicAdd(&h[sorted1[e] >> 10], 1);
    __syncthreads();
    if (tid < 128) cur[tid] = h[tid];
    __syncthreads();
    for (int off = 1; off < 128; off <<= 1) {
        int x = 0;
        if (tid < 128 && tid >= off) x = cur[tid - off];
        __syncthreads();
        if (tid < 128) cur[tid] += x;
        __syncthreads();
    }
    if (tid < 128) {
        int start = beg + cur[tid] - h[tid];  // exclusive
        int c = b * 128 + tid;
        if (c < NCLI) rp_c[c] = start;
        cur[tid] = start;
    }
    if (b == NBKT - 1 && tid == 0) rp_c[NCLI] = end;
    __syncthreads();
    for (int e = beg + tid; e < end; e += 256) {
        int p = sorted1[e];
        int pos = atomicAdd(&cur[p >> 10], 1);
        col[pos] = p & 1023;
    }
}

// ---------------- layer kernels ----------------

__global__ __launch_bounds__(256) void cvt_x(const float4* __restrict__ X4,
                                             uint2* __restrict__ out, int n4) {
    int t = blockIdx.x * 256 + threadIdx.x;
    if (t >= n4) return;
    float4 f = X4[t];
    out[t] = make_uint2(pack_bf2(f.x, f.y), pack_bf2(f.z, f.w));
}

__global__ void mm_small_bf(const float* __restrict__ X, const float* __restrict__ W,
                            unsigned short* __restrict__ Ybf) {
    __shared__ float xr[D];
    int i = blockIdx.x, j = threadIdx.x;
    xr[j] = X[i * D + j];
    __syncthreads();
    float acc = 0.f;
#pragma unroll 8
    for (int k = 0; k < D; k++) acc += xr[k] * W[k * D + j];
    Ybf[i * D + j] = (unsigned short)bf16_rn(acc);
}

// mean over CSR segment of bf16x2 rows -> f32 out.
__global__ __launch_bounds__(512) void mean_agg_bf(const unsigned* __restrict__ tbl,
                                                   const int* __restrict__ rowptr,
                                                   const int* __restrict__ col,
                                                   float* __restrict__ out) {
    __shared__ int cols[512];
    __shared__ float part[8][D];
    int i = blockIdx.x, tid = threadIdx.x;
    int g = tid >> 6, l = tid & 63;
    int beg = rowptr[i], end = rowptr[i + 1];
    float x0 = 0, y0 = 0, x1 = 0, y1 = 0, x2 = 0, y2 = 0, x3 = 0, y3 = 0;
    float x4 = 0, y4 = 0, x5 = 0, y5 = 0, x6 = 0, y6 = 0, x7 = 0, y7 = 0;
    for (int base = beg; base < end; base += 512) {
        int m = end - base;
        if (m > 512) m = 512;
        __syncthreads();
        if (tid < m) cols[tid] = col[base + tid];
        __syncthreads();
        int lo = g * 64;
        int hi = min(lo + 64, m);
        int t = lo;
        for (; t + 8 <= hi; t += 8) {
            unsigned v0 = tbl[(cols[t + 0] << 6) + l];
            unsigned v1 = tbl[(cols[t + 1] << 6) + l];
            unsigned v2 = tbl[(cols[t + 2] << 6) + l];
            unsigned v3 = tbl[(cols[t + 3] << 6) + l];
            unsigned v4 = tbl[(cols[t + 4] << 6) + l];
            unsigned v5 = tbl[(cols[t + 5] << 6) + l];
            unsigned v6 = tbl[(cols[t + 6] << 6) + l];
            unsigned v7 = tbl[(cols[t + 7] << 6) + l];
            x0 += bf_lo(v0); y0 += bf_hi(v0);
            x1 += bf_lo(v1); y1 += bf_hi(v1);
            x2 += bf_lo(v2); y2 += bf_hi(v2);
            x3 += bf_lo(v3); y3 += bf_hi(v3);
            x4 += bf_lo(v4); y4 += bf_hi(v4);
            x5 += bf_lo(v5); y5 += bf_hi(v5);
            x6 += bf_lo(v6); y6 += bf_hi(v6);
            x7 += bf_lo(v7); y7 += bf_hi(v7);
        }
        for (; t < hi; t++) {
            unsigned v = tbl[(cols[t] << 6) + l];
            x0 += bf_lo(v); y0 += bf_hi(v);
        }
    }
    part[g][2 * l]     = ((x0 + x1) + (x2 + x3)) + ((x4 + x5) + (x6 + x7));
    part[g][2 * l + 1] = ((y0 + y1) + (y2 + y3)) + ((y4 + y5) + (y6 + y7));
    __syncthreads();
    if (tid < D) {
        float tot = 0.f;
#pragma unroll
        for (int gg = 0; gg < 8; gg++) tot += part[gg][tid];
        out[i * D + tid] = tot / fmaxf((float)(end - beg), 1.f);
    }
}

__global__ void new_a_kernel(const float* __restrict__ mean_a, const float* xa_old,
                             const float* __restrict__ Wl, const float* __restrict__ Wr,
                             const float* __restrict__ b, float* xa_out) {
    __shared__ float mr[D], xr[D];
    int i = blockIdx.x, j = threadIdx.x;
    mr[j] = mean_a[i * D + j];
    xr[j] = xa_old[i * D + j];
    __syncthreads();
    float acc = b[j];
#pragma unroll 4
    for (int k = 0; k < D; k++) acc += mr[k] * Wl[k * D + j] + xr[k] * Wr[k * D + j];
    xa_out[i * D + j] = leaky(acc);
}

// Y = X @ W + b; row-local => safe in place (Y == X)
__global__ __launch_bounds__(256) void gemm_bias(const float* X, const float* __restrict__ W,
                                                 const float* __restrict__ b, float* Y, int M) {
    __shared__ float xs[32][D];
    int tid = threadIdx.x;
    int m0 = blockIdx.x * 32;
    for (int idx = tid; idx < 32 * D; idx += 256) {
        int r = idx >> 7, c = idx & 127;
        int row = m0 + r;
        xs[r][c] = (row < M) ? X[row * D + c] : 0.f;
    }
    __syncthreads();
    int jg = tid & 31;
    int cg = tid >> 5;
    float a00 = 0, a01 = 0, a02 = 0, a03 = 0;
    float a10 = 0, a11 = 0, a12 = 0, a13 = 0;
    float a20 = 0, a21 = 0, a22 = 0, a23 = 0;
    float a30 = 0, a31 = 0, a32 = 0, a33 = 0;
#pragma unroll 4
    for (int k = 0; k < D; k++) {
        float4 w = *(const float4*)&W[k * D + jg * 4];
        float x0 = xs[cg * 4 + 0][k];
        float x1 = xs[cg * 4 + 1][k];
        float x2 = xs[cg * 4 + 2][k];
        float x3 = xs[cg * 4 + 3][k];
        a00 += x0 * w.x; a01 += x0 * w.y; a02 += x0 * w.z; a03 += x0 * w.w;
        a10 += x1 * w.x; a11 += x1 * w.y; a12 += x1 * w.z; a13 += x1 * w.w;
        a20 += x2 * w.x; a21 += x2 * w.y; a22 += x2 * w.z; a23 += x2 * w.w;
        a30 += x3 * w.x; a31 += x3 * w.y; a32 += x3 * w.z; a33 += x3 * w.w;
    }
    float4 bv = *(const float4*)&b[jg * 4];
    float4 o;
    int row = m0 + cg * 4;
    if (row + 0 < M) { o = make_float4(a00 + bv.x, a01 + bv.y, a02 + bv.z, a03 + bv.w); *(float4*)&Y[(row + 0) * D + jg * 4] = o; }
    if (row + 1 < M) { o = make_float4(a10 + bv.x, a11 + bv.y, a12 + bv.z, a13 + bv.w); *(float4*)&Y[(row + 1) * D + jg * 4] = o; }
    if (row + 2 < M) { o = make_float4(a20 + bv.x, a21 + bv.y, a22 + bv.z, a23 + bv.w); *(float4*)&Y[(row + 2) * D + jg * 4] = o; }
    if (row + 3 < M) { o = make_float4(a30 + bv.x, a31 + bv.y, a32 + bv.z, a33 + bv.w); *(float4*)&Y[(row + 3) * D + jg * 4] = o; }
}

// xc = leaky(Y + mean_e ya_bf[col[e]]). One wave per client; edge indices loaded
// coalesced once per 64-edge chunk and broadcast via shfl (no load in dependent path);
// 8 gathers in flight. LAST=1 fuses the linear head.
template <int LAST>
__global__ __launch_bounds__(256) void agg_c_bf(const unsigned* __restrict__ ya,
                                                const int* __restrict__ rowptr,
                                                const int* __restrict__ col, float* Y,
                                                unsigned* __restrict__ xbf,
                                                const float* __restrict__ Wlin,
                                                const float* __restrict__ blin,
                                                float* __restrict__ out, int E) {
    int l = threadIdx.x & 63;
    int gid = blockIdx.x * 4 + (threadIdx.x >> 6);
    if (gid >= NCLI) return;
    int beg = rowptr[gid], end = rowptr[gid + 1];
    float a0 = 0, b0 = 0, a1 = 0, b1 = 0, a2 = 0, b2 = 0, a3 = 0, b3 = 0;
    float a4 = 0, b4 = 0, a5 = 0, b5 = 0, a6 = 0, b6 = 0, a7 = 0, b7 = 0;
    for (int ch = beg; ch < end; ch += 64) {
        int len = min(64, end - ch);
        int ec = col[min(ch + l, E - 1)];  // coalesced; lanes >= len hold garbage, never used
        int j = 0;
        for (; j + 8 <= len; j += 8) {
            int r0 = __shfl(ec, j + 0), r1 = __shfl(ec, j + 1);
            int r2 = __shfl(ec, j + 2), r3 = __shfl(ec, j + 3);
            int r4 = __shfl(ec, j + 4), r5 = __shfl(ec, j + 5);
            int r6 = __shfl(ec, j + 6), r7 = __shfl(ec, j + 7);
            unsigned v0 = ya[(r0 << 6) + l];
            unsigned v1 = ya[(r1 << 6) + l];
            unsigned v2 = ya[(r2 << 6) + l];
            unsigned v3 = ya[(r3 << 6) + l];
            unsigned v4 = ya[(r4 << 6) + l];
            unsigned v5 = ya[(r5 << 6) + l];
            unsigned v6 = ya[(r6 << 6) + l];
            unsigned v7 = ya[(r7 << 6) + l];
            a0 += bf_lo(v0); b0 += bf_hi(v0);
            a1 += bf_lo(v1); b1 += bf_hi(v1);
            a2 += bf_lo(v2); b2 += bf_hi(v2);
            a3 += bf_lo(v3); b3 += bf_hi(v3);
            a4 += bf_lo(v4); b4 += bf_hi(v4);
            a5 += bf_lo(v5); b5 += bf_hi(v5);
            a6 += bf_lo(v6); b6 += bf_hi(v6);
            a7 += bf_lo(v7); b7 += bf_hi(v7);
        }
        for (; j < len; j++) {
            int r = __shfl(ec, j);
            unsigned v = ya[(r << 6) + l];
            a0 += bf_lo(v); b0 += bf_hi(v);
        }
    }
    float sx = ((a0 + a1) + (a2 + a3)) + ((a4 + a5) + (a6 + a7));
    float sy = ((b0 + b1) + (b2 + b3)) + ((b4 + b5) + (b6 + b7));
    float inv = 1.f / fmaxf((float)(end - beg), 1.f);
    float2 yv = *(float2*)&Y[gid * D + 2 * l];
    float r0 = leaky(yv.x + sx * inv);
    float r1 = leaky(yv.y + sy * inv);
    if (LAST) {
        float2 w = *(const float2*)&Wlin[2 * l];
        float v = r0 * w.x + r1 * w.y;
#pragma unroll
        for (int off = 32; off > 0; off >>= 1) v += __shfl_down(v, off);
        if (l == 0) out[gid] = v + blin[0];
    } else {
        *(float2*)&Y[gid * D + 2 * l] = make_float2(r0, r1);
        xbf[(gid << 6) + l] = pack_bf2(r0, r1);
    }
}

extern "C" void kernel_launch(void* const* d_in, const int* in_sizes, int n_in,
                              void* d_out, int out_size, void* d_ws, size_t ws_size,
                              hipStream_t stream) {
    const float* x_clients = (const float*)d_in[0];
    const float* x_agg     = (const float*)d_in[1];
    const int*   c2a_src   = (const int*)d_in[2];
    const int*   c2a_dst   = (const int*)d_in[3];
    const int*   a2c_src   = (const int*)d_in[4];
    const int*   a2c_dst   = (const int*)d_in[5];
    const float* Wl_c2a    = (const float*)d_in[6];
    const float* Wr_c2a    = (const float*)d_in[7];
    const float* b_c2a     = (const float*)d_in[8];
    const float* Wl_a2c    = (const float*)d_in[9];
    const float* Wr_a2c    = (const float*)d_in[10];
    const float* b_a2c     = (const float*)d_in[11];
    const float* W_lin     = (const float*)d_in[12];
    const float* b_lin     = (const float*)d_in[13];
    float* out = (float*)d_out;
    const int E = in_sizes[2];

    char* p = (char*)d_ws;
    auto alloc = [&](size_t bytes) {
        char* r = p;
        p += (bytes + 255) & ~(size_t)255;
        return r;
    };
    float*    xcA   = (float*)alloc(sizeof(float) * NCLI * D);         // f32 master xc
    unsigned* xcbf  = (unsigned*)alloc(sizeof(unsigned) * NCLI * 64);  // bf16x2 shadow
    float*    xa    = (float*)alloc(sizeof(float) * NAGG * D);
    unsigned short* ya_bf = (unsigned short*)alloc(sizeof(unsigned short) * NAGG * D);
    float*    ma    = (float*)alloc(sizeof(float) * NAGG * D);
    int* cnt_a = (int*)alloc(sizeof(int) * 2048);  // cnt_a[0..1023] + bcnt[1024..]
    int* bcnt  = cnt_a + 1024;
    int* rp_a  = (int*)alloc(sizeof(int) * (NAGG + 1));
    int* cur_a = (int*)alloc(sizeof(int) * NAGG);
    int* brp   = (int*)alloc(sizeof(int) * (NBKT + 1));
    int* bcur  = (int*)alloc(sizeof(int) * NBKT);
    int* rp_c  = (int*)alloc(sizeof(int) * (NCLI + 1));
    int* col_c2a = (int*)alloc(sizeof(int) * E);
    int* col_a2c = (int*)alloc(sizeof(int) * E);
    // sorted1 aliases xcA: lifetime disjoint (CSR build completes before layer-0 gemm writes xcA)
    int* sorted1 = (int*)xcA;

    hipMemsetAsync(cnt_a, 0, sizeof(int) * 2048, stream);

    // bf16 shadow of layer-0 client features
    cvt_x<<<(NCLI * D / 4 + 255) / 256, 256, 0, stream>>>((const float4*)x_clients,
                                                          (uint2*)xcbf, NCLI * D / 4);

    hist_both<<<512, 256, 0, stream>>>(c2a_dst, a2c_dst, E, cnt_a, bcnt);
    scan_both<<<2, 1024, 0, stream>>>(cnt_a, rp_a, cur_a, bcnt, brp, bcur);
    scatter_c2a<<<256, 256, 0, stream>>>(c2a_src, c2a_dst, E, cur_a, col_c2a);
    bucket_scatter<<<256, 256, 0, stream>>>(a2c_src, a2c_dst, E, bcur, sorted1);
    bucket_csr<<<NBKT, 256, 0, stream>>>(brp, sorted1, rp_c, col_a2c);

    const float* xc_old = x_clients;
    const float* xa_old = x_agg;
    for (int l = 0; l < NLAYER; l++) {
        // ya_bf = bf16(xa_old @ Wl_a2c[l])  (folds mean_c @ Wl into gather of ya rows)
        mm_small_bf<<<NAGG, D, 0, stream>>>(xa_old, Wl_a2c + l * D * D, ya_bf);
        // mean_a over c2a edges of bf16 shadow
        mean_agg_bf<<<NAGG, 512, 0, stream>>>(xcbf, rp_a, col_c2a, ma);
        // xa = leaky(mean_a @ Wl_c2a + xa_old @ Wr_c2a + b_c2a)  (in place for l>0)
        new_a_kernel<<<NAGG, D, 0, stream>>>(ma, xa_old, Wl_c2a + l * D * D, Wr_c2a + l * D * D,
                                             b_c2a + l * D, xa);
        // xcA = xc_old @ Wr_a2c + b_a2c  (in place for l>0; row-local)
        gemm_bias<<<(NCLI + 31) / 32, 256, 0, stream>>>(xc_old, Wr_a2c + l * D * D, b_a2c + l * D,
                                                        xcA, NCLI);
        // xcA = leaky(xcA + mean ya); last layer fuses the linear head
        if (l < NLAYER - 1) {
            agg_c_bf<0><<<(NCLI + 3) / 4, 256, 0, stream>>>((const unsigned*)ya_bf, rp_c, col_a2c,
                                                            xcA, xcbf, nullptr, nullptr, nullptr, E);
        } else {
            agg_c_bf<1><<<(NCLI + 3) / 4, 256, 0, stream>>>((const unsigned*)ya_bf, rp_c, col_a2c,
                                                            xcA, nullptr, W_lin, b_lin, out, E);
        }
        xc_old = xcA;
        xa_old = xa;
    }
}

// Round 5
// 762.558 us; speedup vs baseline: 2.2861x; 1.0668x over previous
//
#include <hip/hip_runtime.h>

#define D      128
#define NCLI   100000
#define NAGG   1000
#define NLAYER 3
#define NBKT   782   // ceil(NCLI/128)

typedef short bf16x8 __attribute__((ext_vector_type(8)));
typedef float f32x4 __attribute__((ext_vector_type(4)));

static __device__ __forceinline__ float leaky(float x) { return x >= 0.f ? x : 0.1f * x; }

// ---- bf16 pack/unpack (RNE) ----
static __device__ __forceinline__ unsigned bf16_rn(float f) {
    unsigned u = __float_as_uint(f);
    return (u + 0x7fffu + ((u >> 16) & 1u)) >> 16;
}
static __device__ __forceinline__ float bf_val(unsigned h) { return __uint_as_float(h << 16); }
static __device__ __forceinline__ unsigned pack_bf2(float lo, float hi) {
    return bf16_rn(lo) | (bf16_rn(hi) << 16);
}
static __device__ __forceinline__ float bf_lo(unsigned v) { return __uint_as_float(v << 16); }
static __device__ __forceinline__ float bf_hi(unsigned v) { return __uint_as_float(v & 0xffff0000u); }

// ---------------- CSR build ----------------

__global__ __launch_bounds__(256) void hist_both(const int* __restrict__ c2a_dst,
                                                 const int* __restrict__ a2c_dst, int E,
                                                 int* __restrict__ cnt_a, int* __restrict__ bcnt) {
    __shared__ int h[NAGG + NBKT];
    for (int i = threadIdx.x; i < NAGG + NBKT; i += 256) h[i] = 0;
    __syncthreads();
    int stride = gridDim.x * 256;
    for (int e = blockIdx.x * 256 + threadIdx.x; e < E; e += stride) {
        atomicAdd(&h[c2a_dst[e]], 1);
        atomicAdd(&h[NAGG + (a2c_dst[e] >> 7)], 1);
    }
    __syncthreads();
    for (int i = threadIdx.x; i < NAGG; i += 256)
        if (h[i]) atomicAdd(&cnt_a[i], h[i]);
    for (int i = threadIdx.x; i < NBKT; i += 256)
        if (h[NAGG + i]) atomicAdd(&bcnt[i], h[NAGG + i]);
}

__global__ void scan_both(const int* __restrict__ cnt_a, int* __restrict__ rp_a,
                          int* __restrict__ cur_a, const int* __restrict__ bcnt,
                          int* __restrict__ brp, int* __restrict__ bcur) {
    __shared__ int sh[1024];
    const int* cnt;
    int *rp, *cur, n;
    if (blockIdx.x == 0) { cnt = cnt_a; rp = rp_a; cur = cur_a; n = NAGG; }
    else                 { cnt = bcnt;  rp = brp;  cur = bcur;  n = NBKT; }
    int t = threadIdx.x;
    int v = (t < n) ? cnt[t] : 0;
    sh[t] = v;
    __syncthreads();
    for (int off = 1; off < 1024; off <<= 1) {
        int x = (t >= off) ? sh[t - off] : 0;
        __syncthreads();
        sh[t] += x;
        __syncthreads();
    }
    if (t == 0) { rp[0] = 0; cur[0] = 0; }
    if (t < n) {
        rp[t + 1] = sh[t];
        if (t + 1 < n) cur[t + 1] = sh[t];
    }
}

__global__ __launch_bounds__(256) void scatter_c2a(const int* __restrict__ src,
                                                   const int* __restrict__ dst, int E,
                                                   int* __restrict__ cursor,
                                                   int* __restrict__ col) {
    __shared__ int h[NAGG];
    __shared__ int base[NAGG];
    int tid = threadIdx.x;
    int chunk = (E + gridDim.x - 1) / gridDim.x;
    int e0 = blockIdx.x * chunk;
    int e1 = min(E, e0 + chunk);
    for (int i = tid; i < NAGG; i += 256) h[i] = 0;
    __syncthreads();
    for (int e = e0 + tid; e < e1; e += 256) atomicAdd(&h[dst[e]], 1);
    __syncthreads();
    for (int i = tid; i < NAGG; i += 256) {
        int c = h[i];
        base[i] = c ? atomicAdd(&cursor[i], c) : 0;
    }
    __syncthreads();
    for (int e = e0 + tid; e < e1; e += 256) {
        int pos = atomicAdd(&base[dst[e]], 1);
        col[pos] = src[e];
    }
}

__global__ __launch_bounds__(256) void bucket_scatter(const int* __restrict__ src,
                                                      const int* __restrict__ dst, int E,
                                                      int* __restrict__ bcur,
                                                      int* __restrict__ sorted1) {
    __shared__ int h[NBKT];
    __shared__ int base[NBKT];
    int tid = threadIdx.x;
    int chunk = (E + gridDim.x - 1) / gridDim.x;
    int e0 = blockIdx.x * chunk;
    int e1 = min(E, e0 + chunk);
    for (int i = tid; i < NBKT; i += 256) h[i] = 0;
    __syncthreads();
    for (int e = e0 + tid; e < e1; e += 256) atomicAdd(&h[dst[e] >> 7], 1);
    __syncthreads();
    for (int i = tid; i < NBKT; i += 256) {
        int c = h[i];
        base[i] = c ? atomicAdd(&bcur[i], c) : 0;
    }
    __syncthreads();
    for (int e = e0 + tid; e < e1; e += 256) {
        int d = dst[e];
        int pos = atomicAdd(&base[d >> 7], 1);
        sorted1[pos] = ((d & 127) << 10) | src[e];
    }
}

// per bucket: LDS hist(128) -> LDS scan -> write rp_c -> LDS-cursor scatter
__global__ __launch_bounds__(256) void bucket_csr(const int* __restrict__ brp,
                                                  const int* __restrict__ sorted1,
                                                  int* __restrict__ rp_c,
                                                  int* __restrict__ col) {
    __shared__ int h[128], cur[128];
    int b = blockIdx.x, tid = threadIdx.x;
    if (tid < 128) h[tid] = 0;
    __syncthreads();
    int beg = brp[b], end = brp[b + 1];
    for (int e = beg + tid; e < end; e += 256) atomicAdd(&h[sorted1[e] >> 10], 1);
    __syncthreads();
    if (tid < 128) cur[tid] = h[tid];
    __syncthreads();
    for (int off = 1; off < 128; off <<= 1) {
        int x = 0;
        if (tid < 128 && tid >= off) x = cur[tid - off];
        __syncthreads();
        if (tid < 128) cur[tid] += x;
        __syncthreads();
    }
    if (tid < 128) {
        int start = beg + cur[tid] - h[tid];
        int c = b * 128 + tid;
        if (c < NCLI) rp_c[c] = start;
        cur[tid] = start;
    }
    if (b == NBKT - 1 && tid == 0) rp_c[NCLI] = end;
    __syncthreads();
    for (int e = beg + tid; e < end; e += 256) {
        int p = sorted1[e];
        int pos = atomicAdd(&cur[p >> 10], 1);
        col[pos] = p & 1023;
    }
}

// ---------------- layer kernels ----------------

// x_clients f32 -> hi/lo bf16 tables
__global__ __launch_bounds__(256) void cvt_x(const float4* __restrict__ X4,
                                             uint2* __restrict__ hi, uint2* __restrict__ lo,
                                             int n4) {
    int t = blockIdx.x * 256 + threadIdx.x;
    if (t >= n4) return;
    float4 f = X4[t];
    unsigned h0 = bf16_rn(f.x), h1 = bf16_rn(f.y), h2 = bf16_rn(f.z), h3 = bf16_rn(f.w);
    hi[t] = make_uint2(h0 | (h1 << 16), h2 | (h3 << 16));
    lo[t] = make_uint2(pack_bf2(f.x - bf_val(h0), f.y - bf_val(h1)),
                       pack_bf2(f.z - bf_val(h2), f.w - bf_val(h3)));
}

// Wr_a2c (3 layers, [k][n]) -> transposed hi/lo bf16: Wt[l][0][n][k], Wt[l][1][n][k]
__global__ __launch_bounds__(256) void cvt_w(const float* __restrict__ W,
                                             unsigned short* __restrict__ Wt) {
    int idx = blockIdx.x * 256 + threadIdx.x;
    if (idx >= NLAYER * D * D) return;
    int layer = idx >> 14, rem = idx & (D * D - 1);
    int k = rem >> 7, n = rem & 127;
    float w = W[layer * D * D + k * D + n];
    unsigned h = bf16_rn(w);
    unsigned short* base = Wt + layer * 2 * D * D;
    base[n * D + k] = (unsigned short)h;
    base[D * D + n * D + k] = (unsigned short)bf16_rn(w - bf_val(h));
}

// Fused agg-side: mean gather (c2a) + ya = xa@Wl_a2c + xa_new = leaky(mean@Wl_c2a + xa@Wr_c2a + b)
// one block per agg node; 512 threads = 8 groups x 64 lanes for the gather.
__global__ __launch_bounds__(512) void agg_side(const unsigned* __restrict__ tbl,
                                                const int* __restrict__ rowptr,
                                                const int* __restrict__ col,
                                                const float* xa_old,
                                                const float* __restrict__ Wl_a2c,
                                                const float* __restrict__ Wl_c2a,
                                                const float* __restrict__ Wr_c2a,
                                                const float* __restrict__ b_c2a,
                                                unsigned short* __restrict__ ya_bf,
                                                float* xa_out) {
    __shared__ int cols[512];
    __shared__ float part[8][D];
    __shared__ float mr[D], xr[D];
    int i = blockIdx.x, tid = threadIdx.x;
    int g = tid >> 6, l = tid & 63;
    if (tid < D) xr[tid] = xa_old[i * D + tid];
    int beg = rowptr[i], end = rowptr[i + 1];
    float x0 = 0, y0 = 0, x1 = 0, y1 = 0, x2 = 0, y2 = 0, x3 = 0, y3 = 0;
    float x4 = 0, y4 = 0, x5 = 0, y5 = 0, x6 = 0, y6 = 0, x7 = 0, y7 = 0;
    for (int base = beg; base < end; base += 512) {
        int m = end - base;
        if (m > 512) m = 512;
        __syncthreads();
        if (tid < m) cols[tid] = col[base + tid];
        __syncthreads();
        int lo = g * 64;
        int hi = min(lo + 64, m);
        int t = lo;
        for (; t + 8 <= hi; t += 8) {
            unsigned v0 = tbl[(cols[t + 0] << 6) + l];
            unsigned v1 = tbl[(cols[t + 1] << 6) + l];
            unsigned v2 = tbl[(cols[t + 2] << 6) + l];
            unsigned v3 = tbl[(cols[t + 3] << 6) + l];
            unsigned v4 = tbl[(cols[t + 4] << 6) + l];
            unsigned v5 = tbl[(cols[t + 5] << 6) + l];
            unsigned v6 = tbl[(cols[t + 6] << 6) + l];
            unsigned v7 = tbl[(cols[t + 7] << 6) + l];
            x0 += bf_lo(v0); y0 += bf_hi(v0);
            x1 += bf_lo(v1); y1 += bf_hi(v1);
            x2 += bf_lo(v2); y2 += bf_hi(v2);
            x3 += bf_lo(v3); y3 += bf_hi(v3);
            x4 += bf_lo(v4); y4 += bf_hi(v4);
            x5 += bf_lo(v5); y5 += bf_hi(v5);
            x6 += bf_lo(v6); y6 += bf_hi(v6);
            x7 += bf_lo(v7); y7 += bf_hi(v7);
        }
        for (; t < hi; t++) {
            unsigned v = tbl[(cols[t] << 6) + l];
            x0 += bf_lo(v); y0 += bf_hi(v);
        }
    }
    part[g][2 * l]     = ((x0 + x1) + (x2 + x3)) + ((x4 + x5) + (x6 + x7));
    part[g][2 * l + 1] = ((y0 + y1) + (y2 + y3)) + ((y4 + y5) + (y6 + y7));
    __syncthreads();
    if (tid < D) {
        float tot = 0.f;
#pragma unroll
        for (int gg = 0; gg < 8; gg++) tot += part[gg][tid];
        mr[tid] = tot / fmaxf((float)(end - beg), 1.f);
    }
    __syncthreads();
    if (tid < D) {
        int j = tid;
        float accy = 0.f, accn = b_c2a[j];
#pragma unroll 4
        for (int k = 0; k < D; k++) {
            accy += xr[k] * Wl_a2c[k * D + j];
            accn += mr[k] * Wl_c2a[k * D + j] + xr[k] * Wr_c2a[k * D + j];
        }
        ya_bf[i * D + j] = (unsigned short)bf16_rn(accy);
        xa_out[i * D + j] = leaky(accn);
    }
}

// Y = (Ahi+Alo) @ (Whi+Wlo) + bias via 3 bf16 MFMA products (lo*lo dropped).
// Block: 4 waves, 64 rows x 128 cols. No LDS. A: m=lane&15, k=quad*8+j.
// B from n-major Wt: n=lane&15, k=quad*8+j. C/D: col=lane&15, row=quad*4+reg.
__global__ __launch_bounds__(256) void gemm_mfma(const unsigned short* __restrict__ Ahi,
                                                 const unsigned short* __restrict__ Alo,
                                                 const unsigned short* __restrict__ Wt,
                                                 const float* __restrict__ bias,
                                                 float* __restrict__ Y) {
    int tid = threadIdx.x;
    int wave = tid >> 6, lane = tid & 63;
    int t = lane & 15, q = lane >> 4;
    int m = blockIdx.x * 64 + wave * 16 + t;
    int mc = min(m, NCLI - 1);
    const unsigned short* arh = Ahi + (size_t)mc * D + q * 8;
    const unsigned short* arl = Alo + (size_t)mc * D + q * 8;
    bf16x8 ahi[4], alo[4];
#pragma unroll
    for (int kc = 0; kc < 4; kc++) {
        ahi[kc] = *(const bf16x8*)(arh + kc * 32);
        alo[kc] = *(const bf16x8*)(arl + kc * 32);
    }
    const unsigned short* Wlo = Wt + D * D;
    f32x4 acc[8];
#pragma unroll
    for (int nt = 0; nt < 8; nt++) {
        float bv = bias[nt * 16 + t];
        acc[nt] = (f32x4){bv, bv, bv, bv};
    }
#pragma unroll
    for (int nt = 0; nt < 8; nt++) {
        const unsigned short* brh = Wt + (size_t)(nt * 16 + t) * D + q * 8;
        const unsigned short* brl = Wlo + (size_t)(nt * 16 + t) * D + q * 8;
        bf16x8 bhi[4], blo[4];
#pragma unroll
        for (int kc = 0; kc < 4; kc++) {
            bhi[kc] = *(const bf16x8*)(brh + kc * 32);
            blo[kc] = *(const bf16x8*)(brl + kc * 32);
        }
#pragma unroll
        for (int kc = 0; kc < 4; kc++) {
            acc[nt] = __builtin_amdgcn_mfma_f32_16x16x32_bf16(ahi[kc], bhi[kc], acc[nt], 0, 0, 0);
            acc[nt] = __builtin_amdgcn_mfma_f32_16x16x32_bf16(alo[kc], bhi[kc], acc[nt], 0, 0, 0);
            acc[nt] = __builtin_amdgcn_mfma_f32_16x16x32_bf16(ahi[kc], blo[kc], acc[nt], 0, 0, 0);
        }
    }
    int row0 = blockIdx.x * 64 + wave * 16 + q * 4;
#pragma unroll
    for (int reg = 0; reg < 4; reg++) {
        int row = row0 + reg;
        if (row < NCLI) {
            float* yr = Y + (size_t)row * D + t;
#pragma unroll
            for (int nt = 0; nt < 8; nt++) yr[nt * 16] = acc[nt][reg];
        }
    }
}

// xc = leaky(Y + mean_e ya_bf[col[e]]); writes hi/lo bf16 tables (LAST=0) or fused head (LAST=1)
template <int LAST>
__global__ __launch_bounds__(256) void agg_c_bf(const unsigned* __restrict__ ya,
                                                const int* __restrict__ rowptr,
                                                const int* __restrict__ col,
                                                const float* __restrict__ Y,
                                                unsigned* __restrict__ xhi,
                                                unsigned* __restrict__ xlo,
                                                const float* __restrict__ Wlin,
                                                const float* __restrict__ blin,
                                                float* __restrict__ out, int E) {
    int l = threadIdx.x & 63;
    int gid = blockIdx.x * 4 + (threadIdx.x >> 6);
    if (gid >= NCLI) return;
    int beg = rowptr[gid], end = rowptr[gid + 1];
    float a0 = 0, b0 = 0, a1 = 0, b1 = 0, a2 = 0, b2 = 0, a3 = 0, b3 = 0;
    float a4 = 0, b4 = 0, a5 = 0, b5 = 0, a6 = 0, b6 = 0, a7 = 0, b7 = 0;
    for (int ch = beg; ch < end; ch += 64) {
        int len = min(64, end - ch);
        int ec = col[min(ch + l, E - 1)];
        int j = 0;
        for (; j + 8 <= len; j += 8) {
            int r0 = __shfl(ec, j + 0), r1 = __shfl(ec, j + 1);
            int r2 = __shfl(ec, j + 2), r3 = __shfl(ec, j + 3);
            int r4 = __shfl(ec, j + 4), r5 = __shfl(ec, j + 5);
            int r6 = __shfl(ec, j + 6), r7 = __shfl(ec, j + 7);
            unsigned v0 = ya[(r0 << 6) + l];
            unsigned v1 = ya[(r1 << 6) + l];
            unsigned v2 = ya[(r2 << 6) + l];
            unsigned v3 = ya[(r3 << 6) + l];
            unsigned v4 = ya[(r4 << 6) + l];
            unsigned v5 = ya[(r5 << 6) + l];
            unsigned v6 = ya[(r6 << 6) + l];
            unsigned v7 = ya[(r7 << 6) + l];
            a0 += bf_lo(v0); b0 += bf_hi(v0);
            a1 += bf_lo(v1); b1 += bf_hi(v1);
            a2 += bf_lo(v2); b2 += bf_hi(v2);
            a3 += bf_lo(v3); b3 += bf_hi(v3);
            a4 += bf_lo(v4); b4 += bf_hi(v4);
            a5 += bf_lo(v5); b5 += bf_hi(v5);
            a6 += bf_lo(v6); b6 += bf_hi(v6);
            a7 += bf_lo(v7); b7 += bf_hi(v7);
        }
        for (; j < len; j++) {
            int r = __shfl(ec, j);
            unsigned v = ya[(r << 6) + l];
            a0 += bf_lo(v); b0 += bf_hi(v);
        }
    }
    float sx = ((a0 + a1) + (a2 + a3)) + ((a4 + a5) + (a6 + a7));
    float sy = ((b0 + b1) + (b2 + b3)) + ((b4 + b5) + (b6 + b7));
    float inv = 1.f / fmaxf((float)(end - beg), 1.f);
    float2 yv = *(const float2*)&Y[gid * D + 2 * l];
    float r0 = leaky(yv.x + sx * inv);
    float r1 = leaky(yv.y + sy * inv);
    if (LAST) {
        float2 w = *(const float2*)&Wlin[2 * l];
        float v = r0 * w.x + r1 * w.y;
#pragma unroll
        for (int off = 32; off > 0; off >>= 1) v += __shfl_down(v, off);
        if (l == 0) out[gid] = v + blin[0];
    } else {
        unsigned h0 = bf16_rn(r0), h1 = bf16_rn(r1);
        xhi[(gid << 6) + l] = h0 | (h1 << 16);
        xlo[(gid << 6) + l] = pack_bf2(r0 - bf_val(h0), r1 - bf_val(h1));
    }
}

extern "C" void kernel_launch(void* const* d_in, const int* in_sizes, int n_in,
                              void* d_out, int out_size, void* d_ws, size_t ws_size,
                              hipStream_t stream) {
    const float* x_clients = (const float*)d_in[0];
    const float* x_agg     = (const float*)d_in[1];
    const int*   c2a_src   = (const int*)d_in[2];
    const int*   c2a_dst   = (const int*)d_in[3];
    const int*   a2c_src   = (const int*)d_in[4];
    const int*   a2c_dst   = (const int*)d_in[5];
    const float* Wl_c2a    = (const float*)d_in[6];
    const float* Wr_c2a    = (const float*)d_in[7];
    const float* b_c2a     = (const float*)d_in[8];
    const float* Wl_a2c    = (const float*)d_in[9];
    const float* Wr_a2c    = (const float*)d_in[10];
    const float* b_a2c     = (const float*)d_in[11];
    const float* W_lin     = (const float*)d_in[12];
    const float* b_lin     = (const float*)d_in[13];
    float* out = (float*)d_out;
    const int E = in_sizes[2];

    char* p = (char*)d_ws;
    auto alloc = [&](size_t bytes) {
        char* r = p;
        p += (bytes + 255) & ~(size_t)255;
        return r;
    };
    float*    Yb    = (float*)alloc(sizeof(float) * NCLI * D);         // gemm output (f32)
    unsigned* xc_hi = (unsigned*)alloc(sizeof(unsigned) * NCLI * 64);  // bf16 hi (also gather tbl)
    unsigned* xc_lo = (unsigned*)alloc(sizeof(unsigned) * NCLI * 64);  // bf16 lo
    float*    xa    = (float*)alloc(sizeof(float) * NAGG * D);
    unsigned short* ya_bf = (unsigned short*)alloc(sizeof(unsigned short) * NAGG * D);
    unsigned short* Wt = (unsigned short*)alloc(sizeof(unsigned short) * NLAYER * 2 * D * D);
    int* cnt_a = (int*)alloc(sizeof(int) * 2048);  // cnt_a[0..1023] + bcnt[1024..]
    int* bcnt  = cnt_a + 1024;
    int* rp_a  = (int*)alloc(sizeof(int) * (NAGG + 1));
    int* cur_a = (int*)alloc(sizeof(int) * NAGG);
    int* brp   = (int*)alloc(sizeof(int) * (NBKT + 1));
    int* bcur  = (int*)alloc(sizeof(int) * NBKT);
    int* rp_c  = (int*)alloc(sizeof(int) * (NCLI + 1));
    int* col_c2a = (int*)alloc(sizeof(int) * E);
    int* col_a2c = (int*)alloc(sizeof(int) * E);
    // sorted1 aliases Yb: lifetime disjoint (CSR build completes before layer-0 gemm writes Yb)
    int* sorted1 = (int*)Yb;

    hipMemsetAsync(cnt_a, 0, sizeof(int) * 2048, stream);

    cvt_x<<<(NCLI * D / 4 + 255) / 256, 256, 0, stream>>>((const float4*)x_clients,
                                                          (uint2*)xc_hi, (uint2*)xc_lo,
                                                          NCLI * D / 4);
    cvt_w<<<(NLAYER * D * D + 255) / 256, 256, 0, stream>>>(Wr_a2c, Wt);

    hist_both<<<512, 256, 0, stream>>>(c2a_dst, a2c_dst, E, cnt_a, bcnt);
    scan_both<<<2, 1024, 0, stream>>>(cnt_a, rp_a, cur_a, bcnt, brp, bcur);
    scatter_c2a<<<256, 256, 0, stream>>>(c2a_src, c2a_dst, E, cur_a, col_c2a);
    bucket_scatter<<<256, 256, 0, stream>>>(a2c_src, a2c_dst, E, bcur, sorted1);
    bucket_csr<<<NBKT, 256, 0, stream>>>(brp, sorted1, rp_c, col_a2c);

    const float* xa_old = x_agg;
    for (int l = 0; l < NLAYER; l++) {
        // agg side: mean(c2a) + ya_bf + xa update, one kernel
        agg_side<<<NAGG, 512, 0, stream>>>(xc_hi, rp_a, col_c2a, xa_old,
                                           Wl_a2c + l * D * D, Wl_c2a + l * D * D,
                                           Wr_c2a + l * D * D, b_c2a + l * D, ya_bf, xa);
        // Yb = xc @ Wr_a2c + b_a2c  (split-bf16 MFMA)
        gemm_mfma<<<(NCLI + 63) / 64, 256, 0, stream>>>(
            (const unsigned short*)xc_hi, (const unsigned short*)xc_lo,
            Wt + l * 2 * D * D, b_a2c + l * D, Yb);
        // xc = leaky(Yb + mean ya); last layer fuses the linear head
        if (l < NLAYER - 1) {
            agg_c_bf<0><<<(NCLI + 3) / 4, 256, 0, stream>>>((const unsigned*)ya_bf, rp_c, col_a2c,
                                                            Yb, xc_hi, xc_lo, nullptr, nullptr,
                                                            nullptr, E);
        } else {
            agg_c_bf<1><<<(NCLI + 3) / 4, 256, 0, stream>>>((const unsigned*)ya_bf, rp_c, col_a2c,
                                                            Yb, nullptr, nullptr, W_lin, b_lin,
                                                            out, E);
        }
        xa_old = xa;
    }
}